// Round 9
// baseline (241.200 us; speedup 1.0000x reference)
//
#include <hip/hip_runtime.h>
#include <hip/hip_bf16.h>
#include <cstdint>
#include <cstddef>

typedef unsigned short u16;
typedef __bf16 bf16x8 __attribute__((ext_vector_type(8)));
typedef float  f32x4  __attribute__((ext_vector_type(4)));
typedef u16    u16x8  __attribute__((ext_vector_type(8)));
typedef u16    u16x4  __attribute__((ext_vector_type(4)));
typedef short  s16x4  __attribute__((ext_vector_type(4)));

#define MFMA16(A_, B_, C_) __builtin_amdgcn_mfma_f32_16x16x32_bf16((A_), (B_), (C_), 0, 0, 0)
#define MFMA16K16(A_, B_, C_) __builtin_amdgcn_mfma_f32_16x16x16bf16_1k((A_), (B_), (C_), 0, 0, 0)

#define LOG2E 1.4426950408889634f

__device__ __forceinline__ u16 f2bf(float f) {
  return __builtin_bit_cast(u16, (__bf16)f);
}
__device__ __forceinline__ float bf2f(u16 v) {
  return (float)__builtin_bit_cast(__bf16, v);
}

// async global->LDS, 16B per lane. lds must be wave-uniform base; HW adds lane*16.
__device__ __forceinline__ void async16(u16* lds, const u16* g) {
  __builtin_amdgcn_global_load_lds(
      (const __attribute__((address_space(1))) unsigned int*)g,
      (__attribute__((address_space(3))) unsigned int*)lds, 16, 0, 0);
}

// ---------------- prep kernels ----------------

__global__ void cvt_f32_bf16(const float* __restrict__ src, u16* __restrict__ dst, int n4) {
  int i = blockIdx.x * 256 + threadIdx.x;
  if (i < n4) {
    const float4 v = ((const float4*)src)[i];
    u16x4 o;
    o[0] = f2bf(v.x); o[1] = f2bf(v.y); o[2] = f2bf(v.z); o[3] = f2bf(v.w);
    ((u16x4*)dst)[i] = o;
  }
}

__global__ void bn_prep(const float* __restrict__ g, const float* __restrict__ b,
                        const float* __restrict__ rm, const float* __restrict__ rv,
                        float* __restrict__ alpha, float* __restrict__ beta,
                        int n, float scale) {
  int i = blockIdx.x * 256 + threadIdx.x;
  if (i < n) {
    float a0 = g[i] * rsqrtf(rv[i] + 1e-5f);
    alpha[i] = a0 * scale;
    beta[i]  = (b[i] - rm[i] * a0) * scale;
  }
}

// bias (x log2e) in PV-fragment order: [h][qt3][kt40][tid256][half2][n2][j4]
__global__ void bias_expand_frag(const float* __restrict__ attn_bias, const int* __restrict__ idxs,
                                 u16* __restrict__ bias_frag, int n_off) {
  int i = blockIdx.x * 256 + threadIdx.x;
  if (i >= 8 * 3 * 40 * 256 * 16) return;
  const int e16  = i & 15;
  const int half = e16 >> 3;
  const int nn   = (e16 >> 2) & 1;
  const int j    = e16 & 3;
  const int tid  = (i >> 4) & 255;
  int v = i >> 12;          // (h*3+qt)*40 + kt
  const int kt = v % 40; v /= 40;
  const int qt = v % 3;
  const int h  = v / 3;
  const int w = tid >> 6, lr = (tid >> 4) & 3, lc = tid & 15;
  int q = qt * 128 + w * 32 + half * 16 + lc;
  if (q > 319) q = 319;
  const int k = kt * 32 + nn * 16 + lr * 4 + j;
  bias_frag[i] = f2bf(attn_bias[h * n_off + idxs[q * 1280 + k]] * LOG2E);
}

// ---------------- GEMM 1: kv = x @ W_kv^T, BN, scatter to K-phys / V-phys ----------------
// Per (bh, kt32): K = 32 rows x 64ch, 16B chunk c at c^(r&7)            (b128 reads)
// V = 128 d-rows x 32 keys (64B), 8B chunk hc at (hc+(d>>1))&7          (b64 reads, conflict-free)

__global__ __launch_bounds__(256) void gemm_kv(
    const u16* __restrict__ A, const u16* __restrict__ Wt,
    const float* __restrict__ alpha, const float* __restrict__ beta,
    u16* __restrict__ k_buf, u16* __restrict__ vt_buf) {
  __shared__ __align__(16) u16 As[128 * 64];
  __shared__ __align__(16) u16 Bs[128 * 64];
  const int tid  = threadIdx.x;
  const int lane = tid & 63;
  const int w    = tid >> 6;
  const int wr   = (w >> 1) * 64, wc = (w & 1) * 64;
  const int lr   = lane >> 4, lc = lane & 15;
  const int m0   = blockIdx.x * 128;
  const int n0   = blockIdx.y * 128;
  const int scol  = (lane & 7) * 8;
  f32x4 acc[4][4] = {};

  for (int kt = 0; kt < 256; kt += 64) {
    if (kt) __syncthreads();
#pragma unroll
    for (int i = 0; i < 4; ++i) {
      const int row = w * 32 + i * 8 + (lane >> 3);
      async16(&As[(w * 32 + i * 8) * 64], A  + (size_t)(m0 + row) * 256 + kt + scol);
      async16(&Bs[(w * 32 + i * 8) * 64], Wt + (size_t)(n0 + row) * 256 + kt + scol);
    }
    __syncthreads();
#pragma unroll
    for (int kk = 0; kk < 2; ++kk) {
      bf16x8 af[4], bff[4];
#pragma unroll
      for (int m = 0; m < 4; ++m)
        af[m] = *(const bf16x8*)(&As[(wr + m * 16 + lc) * 64 + kk * 32 + lr * 8]);
#pragma unroll
      for (int n = 0; n < 4; ++n)
        bff[n] = *(const bf16x8*)(&Bs[(wc + n * 16 + lc) * 64 + kk * 32 + lr * 8]);
#pragma unroll
      for (int m = 0; m < 4; ++m)
#pragma unroll
        for (int n = 0; n < 4; ++n)
          acc[m][n] = MFMA16(af[m], bff[n], acc[m][n]);
    }
  }

  const int jr = lr * 4;
#pragma unroll
  for (int m = 0; m < 4; ++m) {
    const int r0  = m0 + wr + m * 16 + jr;
    const int b   = r0 / 1280;
    const int np0 = r0 - b * 1280;          // global key, 4-aligned
    const int kt  = np0 >> 5;
    const int kl  = np0 & 31;               // key-in-tile, 4-aligned
#pragma unroll
    for (int n = 0; n < 4; ++n) {
      const int c    = n0 + wc + n * 16 + lc;
      const float al = alpha[c], be = beta[c];
      const int head = c / 192;
      const int off  = c - head * 192;
      const size_t bh = (size_t)(b * 8 + head);
      if (off < 64) {
        const size_t base = ((bh * 40 + kt) << 11);
#pragma unroll
        for (int j = 0; j < 4; ++j) {
          const int r = kl + j;
          k_buf[base + (r << 6) + ((((off >> 3) ^ (r & 7)) << 3)) + (off & 7)] =
              f2bf(acc[m][n][j] * al + be);
        }
      } else {
        const int d = off - 64;
        u16x4 pk;
#pragma unroll
        for (int j = 0; j < 4; ++j) pk[j] = f2bf(acc[m][n][j] * al + be);
        const size_t dst = ((size_t)(bh * 40 + kt) << 12) + d * 32 +
                           ((((kl >> 2) + (d >> 1)) & 7) << 2);
        *(u16x4*)(&vt_buf[dst]) = pk;
      }
    }
  }
}

// ---------------- GEMM 2: q = subsample(x) @ W_q^T, BN, *(0.125*log2e folded) ----------------

__device__ __forceinline__ int sub_src_row(int qr) {
  if (qr < 256) return ((qr >> 4) * 64) + ((qr & 15) * 2);
  int rr = qr - 256;
  return 1024 + ((rr >> 3) * 32) + ((rr & 7) * 2);
}

__global__ __launch_bounds__(256) void gemm_q(
    const u16* __restrict__ X, const u16* __restrict__ Wt,
    const float* __restrict__ alpha, const float* __restrict__ beta,
    u16* __restrict__ q_buf) {
  __shared__ __align__(16) u16 As[128 * 64];
  __shared__ __align__(16) u16 Bs[128 * 64];
  const int tid  = threadIdx.x;
  const int lane = tid & 63;
  const int w    = tid >> 6;
  const int wr   = (w >> 1) * 64, wc = (w & 1) * 64;
  const int lr   = lane >> 4, lc = lane & 15;
  const int m0   = blockIdx.x * 128;
  const int n0   = blockIdx.y * 128;
  const int scol  = (lane & 7) * 8;
  f32x4 acc[4][4] = {};

  for (int kt = 0; kt < 256; kt += 64) {
    if (kt) __syncthreads();
#pragma unroll
    for (int i = 0; i < 4; ++i) {
      const int row = w * 32 + i * 8 + (lane >> 3);
      const int gr  = m0 + row;
      const int bb  = gr / 320;
      const int qr  = gr - bb * 320;
      async16(&As[(w * 32 + i * 8) * 64],
              X + (size_t)(bb * 1280 + sub_src_row(qr)) * 256 + kt + scol);
      async16(&Bs[(w * 32 + i * 8) * 64], Wt + (size_t)(n0 + row) * 256 + kt + scol);
    }
    __syncthreads();
#pragma unroll
    for (int kk = 0; kk < 2; ++kk) {
      bf16x8 af[4], bff[4];
#pragma unroll
      for (int m = 0; m < 4; ++m)
        af[m] = *(const bf16x8*)(&As[(wr + m * 16 + lc) * 64 + kk * 32 + lr * 8]);
#pragma unroll
      for (int n = 0; n < 4; ++n)
        bff[n] = *(const bf16x8*)(&Bs[(wc + n * 16 + lc) * 64 + kk * 32 + lr * 8]);
#pragma unroll
      for (int m = 0; m < 4; ++m)
#pragma unroll
        for (int n = 0; n < 4; ++n)
          acc[m][n] = MFMA16(af[m], bff[n], acc[m][n]);
    }
  }

  const int jr = lr * 4;
#pragma unroll
  for (int m = 0; m < 4; ++m) {
#pragma unroll
    for (int n = 0; n < 4; ++n) {
      const int c    = n0 + wc + n * 16 + lc;   // < 512
      const float al = alpha[c], be = beta[c];
      const int head = c >> 6, kd = c & 63;
#pragma unroll
      for (int j = 0; j < 4; ++j) {
        const int r  = m0 + wr + m * 16 + jr + j;
        const int b  = r / 320;
        const int qr = r - b * 320;
        q_buf[((size_t)(b * 8 + head) * 320 + qr) * 64 + kd] = f2bf(acc[m][n][j] * al + be);
      }
    }
  }
}

// ---------------- attention ----------------
// Block = 128 q-rows (4 waves x 2 halves of 16). KVBLK=32, 40 tiles.
// Swapped QK^T, in-reg P, K=16 PV, no-max exp2 softmax, bias as MFMA C-init.
// T4: 3-buffer LDS ring, 2-deep gload_lds prefetch, raw s_barrier +
// counted "s_waitcnt vmcnt(5) lgkmcnt(0)" (3 lds-loads + 2 bias loads/wave
// stay in flight across the barrier; lgkmcnt(0) closes the DMA WAR window).

__global__ __launch_bounds__(256) void attn_kernel(
    const u16* __restrict__ q_buf, const u16* __restrict__ kphys,
    const u16* __restrict__ vphys, const u16* __restrict__ bias_frag,
    u16* __restrict__ o_buf) {
  __shared__ __align__(16) u16 Kb[3][2048];
  __shared__ __align__(16) u16 Vb[3][4096];
  const int tid  = threadIdx.x;
  const int lane = tid & 63;
  const int w    = tid >> 6;
  const int lr   = lane >> 4, lc = lane & 15, jr = lr * 4;
  // XCD swizzle: 96 consecutive per XCD -> 32 (b,h) groups of 3 q-tiles
  const int g   = blockIdx.x;
  const int f   = (g & 7) * 96 + (g >> 3);
  const int qt  = f % 3;
  const int bh_ = f / 3;
  const int h = bh_ & 7, b = bh_ >> 3;
  const size_t bh = (size_t)bh_;

  bf16x8 bq[2][2];
#pragma unroll
  for (int hf = 0; hf < 2; ++hf) {
    int q = qt * 128 + w * 32 + hf * 16 + lc;
    if (q > 319) q = 319;
    const u16* qp = q_buf + (bh * 320 + q) * 64 + lr * 8;
    bq[hf][0] = *(const bf16x8*)(qp);
    bq[hf][1] = *(const bf16x8*)(qp + 32);
  }

  f32x4 oacc[2][8] = {};
  float lacc[2] = {0.f, 0.f};

  const u16* kt_base   = kphys + bh * (40 * 2048);
  const u16* vt_base   = vphys + bh * (40 * 4096);
  const u16* bias_base = bias_frag + (((size_t)(h * 3 + qt) * 40) * 256 + tid) * 16;

  u16x8 bbA[2], bbB[2];

  auto issue = [&](int buf, int kt) {
    async16(&Kb[buf][w * 512], kt_base + kt * 2048 + w * 512 + lane * 8);
    const u16* vs = vt_base + kt * 4096 + (w * 2) * 512 + lane * 8;
    async16(&Vb[buf][(w * 2) * 512], vs);
    async16(&Vb[buf][(w * 2 + 1) * 512], vs + 512);
  };
  auto gbias = [&](int kt, u16x8* dst) {
    const u16* bp = bias_base + (size_t)kt * 4096;
    dst[0] = *(const u16x8*)(bp);
    dst[1] = *(const u16x8*)(bp + 8);
  };

  auto compute = [&](int buf, const u16x8* bb) {
    const u16* Ksb = Kb[buf];
    const u16* Vsb = Vb[buf];

    // S^T = K Q^T with bias as C-init; n in {0,1} key-chunks of 16
    f32x4 s[2][2];
    __builtin_amdgcn_s_setprio(1);
#pragma unroll
    for (int n = 0; n < 2; ++n) {
      const u16* kp = Ksb + (n * 16 + lc) * 64;
      const bf16x8 kf0 = *(const bf16x8*)(kp + ((lr ^ (lc & 7)) << 3));
      const bf16x8 kf1 = *(const bf16x8*)(kp + (((4 + lr) ^ (lc & 7)) << 3));
#pragma unroll
      for (int hf = 0; hf < 2; ++hf) {
        const u16* bptr = (const u16*)bb;
        f32x4 t;
#pragma unroll
        for (int j = 0; j < 4; ++j) t[j] = bf2f(bptr[hf * 8 + n * 4 + j]);
        t = MFMA16(kf0, bq[hf][0], t);
        t = MFMA16(kf1, bq[hf][1], t);
        s[hf][n] = t;
      }
    }
    __builtin_amdgcn_s_setprio(0);

    // P = exp2(S') in-register; in-lane partial row-sum
    s16x4 pa[2][2];
#pragma unroll
    for (int hf = 0; hf < 2; ++hf) {
      float ssum = 0.f;
#pragma unroll
      for (int n = 0; n < 2; ++n) {
        u16x4 pk;
#pragma unroll
        for (int j = 0; j < 4; ++j) {
          const float e = exp2f(s[hf][n][j]);
          ssum += e;
          pk[j] = f2bf(e);
        }
        pa[hf][n] = __builtin_bit_cast(s16x4, pk);
      }
      lacc[hf] += ssum;
    }

    // PV: V b64 reads shared by both halves; rotation (hc+(d>>1))&7 conflict-free
    __builtin_amdgcn_s_setprio(1);
#pragma unroll
    for (int nc = 0; nc < 8; ++nc) {
      const int d = nc * 16 + lc;
      const u16* vrow = Vsb + d * 32;
#pragma unroll
      for (int t = 0; t < 2; ++t) {
        const int ph = (t * 4 + lr + (d >> 1)) & 7;
        const s16x4 vf = __builtin_bit_cast(s16x4, *(const u16x4*)(vrow + ph * 4));
        oacc[0][nc] = MFMA16K16(pa[0][t], vf, oacc[0][nc]);
        oacc[1][nc] = MFMA16K16(pa[1][t], vf, oacc[1][nc]);
      }
    }
    __builtin_amdgcn_s_setprio(0);
  };

#define WAITBAR(N)                                                       \
  asm volatile("s_waitcnt vmcnt(" #N ") lgkmcnt(0)" ::: "memory");       \
  __builtin_amdgcn_s_barrier();

  // prologue: 2 tiles in flight
  issue(0, 0);
  issue(1, 1);
  gbias(0, bbA);
  WAITBAR(5)   // tile0's 3 lds done; tile1's 3 + bias0's 2 remain

#pragma unroll 1
  for (int t = 0; t < 38; t += 2) {
    issue((t + 2) % 3, t + 2);
    gbias(t + 1, bbB);
    compute(t % 3, bbA);
    WAITBAR(5)
    issue((t + 3) % 3, t + 3);
    gbias(t + 2, bbA);
    compute((t + 1) % 3, bbB);
    WAITBAR(5)
  }
  // tail: tiles 38, 39 (no further lds issues)
  gbias(39, bbB);
  compute(38 % 3, bbA);
  WAITBAR(2)   // drain tile39's 3 lds; bias39's 2 remain
  compute(39 % 3, bbB);
#undef WAITBAR

#pragma unroll
  for (int hf = 0; hf < 2; ++hf) {
    float l = lacc[hf];
    l += __shfl_xor(l, 16);
    l += __shfl_xor(l, 32);
    float invl[4];
#pragma unroll
    for (int j = 0; j < 4; ++j) invl[j] = 1.f / __shfl(l, jr + j);
#pragma unroll
    for (int nc = 0; nc < 8; ++nc)
#pragma unroll
      for (int j = 0; j < 4; ++j) {
        const int qrow = qt * 128 + w * 32 + hf * 16 + jr + j;
        if (qrow < 320) {
          const float xv = oacc[hf][nc][j] * invl[j];
          const float hs = xv * fminf(fmaxf(xv + 3.f, 0.f), 6.f) * (1.f / 6.f);
          o_buf[((size_t)b * 320 + qrow) * 1024 + h * 128 + nc * 16 + lc] = f2bf(hs);
        }
      }
  }
}

// ---------------- GEMM 3: out = hswish(o) @ W_p^T, BN (f32 out) ----------------

__global__ __launch_bounds__(256) void gemm_p(
    const u16* __restrict__ O, const u16* __restrict__ Wt,
    const float* __restrict__ alpha, const float* __restrict__ beta,
    float* __restrict__ out) {
  __shared__ __align__(16) u16 As[128 * 64];
  __shared__ __align__(16) u16 Bs[128 * 64];
  const int tid  = threadIdx.x;
  const int lane = tid & 63;
  const int w    = tid >> 6;
  const int wr   = (w >> 1) * 64, wc = (w & 1) * 64;
  const int lr   = lane >> 4, lc = lane & 15;
  const int m0   = blockIdx.x * 128;
  const int n0   = blockIdx.y * 128;
  const int scol  = (lane & 7) * 8;
  f32x4 acc[4][4] = {};

  for (int kt = 0; kt < 1024; kt += 64) {
    if (kt) __syncthreads();
#pragma unroll
    for (int i = 0; i < 4; ++i) {
      const int row = w * 32 + i * 8 + (lane >> 3);
      async16(&As[(w * 32 + i * 8) * 64], O  + (size_t)(m0 + row) * 1024 + kt + scol);
      async16(&Bs[(w * 32 + i * 8) * 64], Wt + (size_t)(n0 + row) * 1024 + kt + scol);
    }
    __syncthreads();
#pragma unroll
    for (int kk = 0; kk < 2; ++kk) {
      bf16x8 af[4], bff[4];
#pragma unroll
      for (int m = 0; m < 4; ++m)
        af[m] = *(const bf16x8*)(&As[(wr + m * 16 + lc) * 64 + kk * 32 + lr * 8]);
#pragma unroll
      for (int n = 0; n < 4; ++n)
        bff[n] = *(const bf16x8*)(&Bs[(wc + n * 16 + lc) * 64 + kk * 32 + lr * 8]);
#pragma unroll
      for (int m = 0; m < 4; ++m)
#pragma unroll
        for (int n = 0; n < 4; ++n)
          acc[m][n] = MFMA16(af[m], bff[n], acc[m][n]);
    }
  }

  const int jr = lr * 4;
#pragma unroll
  for (int m = 0; m < 4; ++m) {
#pragma unroll
    for (int n = 0; n < 4; ++n) {
      const int c = n0 + wc + n * 16 + lc;   // < 384
      const float al = alpha[c], be = beta[c];
#pragma unroll
      for (int j = 0; j < 4; ++j) {
        const int r = m0 + wr + m * 16 + jr + j;
        out[(size_t)r * 384 + c] = acc[m][n][j] * al + be;
      }
    }
  }
}

// ---------------- launch ----------------

extern "C" void kernel_launch(void* const* d_in, const int* in_sizes, int n_in,
                              void* d_out, int out_size, void* d_ws, size_t ws_size,
                              hipStream_t stream) {
  const float* x      = (const float*)d_in[0];
  const float* W_kv   = (const float*)d_in[1];
  const float* g_kv   = (const float*)d_in[2];
  const float* b_kv   = (const float*)d_in[3];
  const float* rm_kv  = (const float*)d_in[4];
  const float* rv_kv  = (const float*)d_in[5];
  const float* W_q    = (const float*)d_in[6];
  const float* g_q    = (const float*)d_in[7];
  const float* b_q    = (const float*)d_in[8];
  const float* rm_q   = (const float*)d_in[9];
  const float* rv_q   = (const float*)d_in[10];
  const float* W_p    = (const float*)d_in[11];
  const float* g_p    = (const float*)d_in[12];
  const float* b_p    = (const float*)d_in[13];
  const float* rm_p   = (const float*)d_in[14];
  const float* rv_p   = (const float*)d_in[15];
  const float* attn_bias = (const float*)d_in[16];
  const int*   bias_idxs = (const int*)d_in[17];
  const int n_off = in_sizes[16] / 8;

  char* ws = (char*)d_ws;
  size_t off = 0;
  auto alloc = [&](size_t bytes) -> void* {
    void* p = ws + off;
    off += (bytes + 255) & ~(size_t)255;
    return p;
  };
  u16* x_bf    = (u16*)alloc((size_t)40960 * 256 * 2);
  u16* wkv_bf  = (u16*)alloc((size_t)1536 * 256 * 2);
  u16* wq_bf   = (u16*)alloc((size_t)512 * 256 * 2);
  u16* wp_bf   = (u16*)alloc((size_t)384 * 1024 * 2);
  float* al_kv = (float*)alloc(1536 * 4);
  float* be_kv = (float*)alloc(1536 * 4);
  float* al_q  = (float*)alloc(512 * 4);
  float* be_q  = (float*)alloc(512 * 4);
  float* al_p  = (float*)alloc(384 * 4);
  float* be_p  = (float*)alloc(384 * 4);
  u16* k_buf   = (u16*)alloc((size_t)256 * 40 * 2048 * 2);
  u16* vt_buf  = (u16*)alloc((size_t)256 * 40 * 4096 * 2);
  u16* q_buf   = (u16*)alloc((size_t)32 * 8 * 320 * 64 * 2);
  u16* bias_fr = (u16*)alloc((size_t)8 * 3 * 40 * 256 * 16 * 2);
  u16* o_buf   = (u16*)alloc((size_t)32 * 320 * 1024 * 2);
  (void)ws_size; (void)n_in; (void)out_size;

  cvt_f32_bf16<<<(2621440 + 255) / 256, 256, 0, stream>>>(x, x_bf, 2621440);
  cvt_f32_bf16<<<(98304 + 255) / 256, 256, 0, stream>>>(W_kv, wkv_bf, 98304);
  cvt_f32_bf16<<<(32768 + 255) / 256, 256, 0, stream>>>(W_q, wq_bf, 32768);
  cvt_f32_bf16<<<(98304 + 255) / 256, 256, 0, stream>>>(W_p, wp_bf, 98304);
  bn_prep<<<6, 256, 0, stream>>>(g_kv, b_kv, rm_kv, rv_kv, al_kv, be_kv, 1536, 1.0f);
  bn_prep<<<2, 256, 0, stream>>>(g_q, b_q, rm_q, rv_q, al_q, be_q, 512, 0.125f * LOG2E);
  bn_prep<<<2, 256, 0, stream>>>(g_p, b_p, rm_p, rv_p, al_p, be_p, 384, 1.0f);
  bias_expand_frag<<<(7864320 + 255) / 256, 256, 0, stream>>>(attn_bias, bias_idxs, bias_fr, n_off);

  gemm_kv<<<dim3(320, 12), 256, 0, stream>>>(x_bf, wkv_bf, al_kv, be_kv, k_buf, vt_buf);
  gemm_q<<<dim3(80, 4), 256, 0, stream>>>(x_bf, wq_bf, al_q, be_q, q_buf);
  attn_kernel<<<dim3(768), 256, 0, stream>>>(q_buf, k_buf, vt_buf, bias_fr, o_buf);
  gemm_p<<<dim3(80, 3), 256, 0, stream>>>(o_buf, wp_bf, al_p, be_p, (float*)d_out);
}

// Round 10
// 208.636 us; speedup vs baseline: 1.1561x; 1.1561x over previous
//
#include <hip/hip_runtime.h>
#include <hip/hip_bf16.h>
#include <cstdint>
#include <cstddef>

typedef unsigned short u16;
typedef __bf16 bf16x8 __attribute__((ext_vector_type(8)));
typedef float  f32x4  __attribute__((ext_vector_type(4)));
typedef u16    u16x8  __attribute__((ext_vector_type(8)));
typedef u16    u16x4  __attribute__((ext_vector_type(4)));
typedef short  s16x4  __attribute__((ext_vector_type(4)));

#define MFMA16(A_, B_, C_) __builtin_amdgcn_mfma_f32_16x16x32_bf16((A_), (B_), (C_), 0, 0, 0)
#define MFMA16K16(A_, B_, C_) __builtin_amdgcn_mfma_f32_16x16x16bf16_1k((A_), (B_), (C_), 0, 0, 0)

#define LOG2E 1.4426950408889634f

__device__ __forceinline__ u16 f2bf(float f) {
  return __builtin_bit_cast(u16, (__bf16)f);
}
__device__ __forceinline__ float bf2f(u16 v) {
  return (float)__builtin_bit_cast(__bf16, v);
}

// async global->LDS, 16B per lane. lds must be wave-uniform base; HW adds lane*16.
__device__ __forceinline__ void async16(u16* lds, const u16* g) {
  __builtin_amdgcn_global_load_lds(
      (const __attribute__((address_space(1))) unsigned int*)g,
      (__attribute__((address_space(3))) unsigned int*)lds, 16, 0, 0);
}

// ---------------- prep kernels ----------------

__global__ void cvt_f32_bf16(const float* __restrict__ src, u16* __restrict__ dst, int n4) {
  int i = blockIdx.x * 256 + threadIdx.x;
  if (i < n4) {
    const float4 v = ((const float4*)src)[i];
    u16x4 o;
    o[0] = f2bf(v.x); o[1] = f2bf(v.y); o[2] = f2bf(v.z); o[3] = f2bf(v.w);
    ((u16x4*)dst)[i] = o;
  }
}

__global__ void bn_prep(const float* __restrict__ g, const float* __restrict__ b,
                        const float* __restrict__ rm, const float* __restrict__ rv,
                        float* __restrict__ alpha, float* __restrict__ beta,
                        int n, float scale) {
  int i = blockIdx.x * 256 + threadIdx.x;
  if (i < n) {
    float a0 = g[i] * rsqrtf(rv[i] + 1e-5f);
    alpha[i] = a0 * scale;
    beta[i]  = (b[i] - rm[i] * a0) * scale;
  }
}

// bias (x log2e) in PV-fragment order: [h][qt5][kt40][tid256][nn2*j4]
__global__ void bias_expand_frag(const float* __restrict__ attn_bias, const int* __restrict__ idxs,
                                 u16* __restrict__ bias_frag, int n_off) {
  int i = blockIdx.x * 256 + threadIdx.x;
  if (i >= 8 * 5 * 40 * 256 * 8) return;
  const int e8  = i & 7;
  const int nn  = e8 >> 2;
  const int j   = e8 & 3;
  const int tid = (i >> 3) & 255;
  int v = i >> 11;          // (h*5+qt)*40 + kt
  const int kt = v % 40; v /= 40;
  const int qt = v % 5;
  const int h  = v / 5;
  const int w = tid >> 6, lr = (tid >> 4) & 3, lc = tid & 15;
  const int q = qt * 64 + w * 16 + lc;
  const int k = kt * 32 + nn * 16 + lr * 4 + j;
  bias_frag[i] = f2bf(attn_bias[h * n_off + idxs[q * 1280 + k]] * LOG2E);
}

// ---------------- GEMM 1: kv = x @ W_kv^T, BN, scatter to K-phys / V-phys ----------------
// Per (bh, kt32): K = 32 rows x 64ch, 16B chunk c at c^(r&7)            (b128 reads)
// V = 128 d-rows x 32 keys (64B), 8B chunk hc at (hc+(d>>1))&7          (b64 reads, conflict-free)

__global__ __launch_bounds__(256) void gemm_kv(
    const u16* __restrict__ A, const u16* __restrict__ Wt,
    const float* __restrict__ alpha, const float* __restrict__ beta,
    u16* __restrict__ k_buf, u16* __restrict__ vt_buf) {
  __shared__ __align__(16) u16 As[128 * 64];
  __shared__ __align__(16) u16 Bs[128 * 64];
  const int tid  = threadIdx.x;
  const int lane = tid & 63;
  const int w    = tid >> 6;
  const int wr   = (w >> 1) * 64, wc = (w & 1) * 64;
  const int lr   = lane >> 4, lc = lane & 15;
  const int m0   = blockIdx.x * 128;
  const int n0   = blockIdx.y * 128;
  const int scol  = (lane & 7) * 8;
  f32x4 acc[4][4] = {};

  for (int kt = 0; kt < 256; kt += 64) {
    if (kt) __syncthreads();
#pragma unroll
    for (int i = 0; i < 4; ++i) {
      const int row = w * 32 + i * 8 + (lane >> 3);
      async16(&As[(w * 32 + i * 8) * 64], A  + (size_t)(m0 + row) * 256 + kt + scol);
      async16(&Bs[(w * 32 + i * 8) * 64], Wt + (size_t)(n0 + row) * 256 + kt + scol);
    }
    __syncthreads();
#pragma unroll
    for (int kk = 0; kk < 2; ++kk) {
      bf16x8 af[4], bff[4];
#pragma unroll
      for (int m = 0; m < 4; ++m)
        af[m] = *(const bf16x8*)(&As[(wr + m * 16 + lc) * 64 + kk * 32 + lr * 8]);
#pragma unroll
      for (int n = 0; n < 4; ++n)
        bff[n] = *(const bf16x8*)(&Bs[(wc + n * 16 + lc) * 64 + kk * 32 + lr * 8]);
#pragma unroll
      for (int m = 0; m < 4; ++m)
#pragma unroll
        for (int n = 0; n < 4; ++n)
          acc[m][n] = MFMA16(af[m], bff[n], acc[m][n]);
    }
  }

  const int jr = lr * 4;
#pragma unroll
  for (int m = 0; m < 4; ++m) {
    const int r0  = m0 + wr + m * 16 + jr;
    const int b   = r0 / 1280;
    const int np0 = r0 - b * 1280;          // global key, 4-aligned
    const int kt  = np0 >> 5;
    const int kl  = np0 & 31;               // key-in-tile, 4-aligned
#pragma unroll
    for (int n = 0; n < 4; ++n) {
      const int c    = n0 + wc + n * 16 + lc;
      const float al = alpha[c], be = beta[c];
      const int head = c / 192;
      const int off  = c - head * 192;
      const size_t bh = (size_t)(b * 8 + head);
      if (off < 64) {
        const size_t base = ((bh * 40 + kt) << 11);
#pragma unroll
        for (int j = 0; j < 4; ++j) {
          const int r = kl + j;
          k_buf[base + (r << 6) + ((((off >> 3) ^ (r & 7)) << 3)) + (off & 7)] =
              f2bf(acc[m][n][j] * al + be);
        }
      } else {
        const int d = off - 64;
        u16x4 pk;
#pragma unroll
        for (int j = 0; j < 4; ++j) pk[j] = f2bf(acc[m][n][j] * al + be);
        const size_t dst = ((size_t)(bh * 40 + kt) << 12) + d * 32 +
                           ((((kl >> 2) + (d >> 1)) & 7) << 2);
        *(u16x4*)(&vt_buf[dst]) = pk;
      }
    }
  }
}

// ---------------- GEMM 2: q = subsample(x) @ W_q^T, BN, *(0.125*log2e folded) ----------------

__device__ __forceinline__ int sub_src_row(int qr) {
  if (qr < 256) return ((qr >> 4) * 64) + ((qr & 15) * 2);
  int rr = qr - 256;
  return 1024 + ((rr >> 3) * 32) + ((rr & 7) * 2);
}

__global__ __launch_bounds__(256) void gemm_q(
    const u16* __restrict__ X, const u16* __restrict__ Wt,
    const float* __restrict__ alpha, const float* __restrict__ beta,
    u16* __restrict__ q_buf) {
  __shared__ __align__(16) u16 As[128 * 64];
  __shared__ __align__(16) u16 Bs[128 * 64];
  const int tid  = threadIdx.x;
  const int lane = tid & 63;
  const int w    = tid >> 6;
  const int wr   = (w >> 1) * 64, wc = (w & 1) * 64;
  const int lr   = lane >> 4, lc = lane & 15;
  const int m0   = blockIdx.x * 128;
  const int n0   = blockIdx.y * 128;
  const int scol  = (lane & 7) * 8;
  f32x4 acc[4][4] = {};

  for (int kt = 0; kt < 256; kt += 64) {
    if (kt) __syncthreads();
#pragma unroll
    for (int i = 0; i < 4; ++i) {
      const int row = w * 32 + i * 8 + (lane >> 3);
      const int gr  = m0 + row;
      const int bb  = gr / 320;
      const int qr  = gr - bb * 320;
      async16(&As[(w * 32 + i * 8) * 64],
              X + (size_t)(bb * 1280 + sub_src_row(qr)) * 256 + kt + scol);
      async16(&Bs[(w * 32 + i * 8) * 64], Wt + (size_t)(n0 + row) * 256 + kt + scol);
    }
    __syncthreads();
#pragma unroll
    for (int kk = 0; kk < 2; ++kk) {
      bf16x8 af[4], bff[4];
#pragma unroll
      for (int m = 0; m < 4; ++m)
        af[m] = *(const bf16x8*)(&As[(wr + m * 16 + lc) * 64 + kk * 32 + lr * 8]);
#pragma unroll
      for (int n = 0; n < 4; ++n)
        bff[n] = *(const bf16x8*)(&Bs[(wc + n * 16 + lc) * 64 + kk * 32 + lr * 8]);
#pragma unroll
      for (int m = 0; m < 4; ++m)
#pragma unroll
        for (int n = 0; n < 4; ++n)
          acc[m][n] = MFMA16(af[m], bff[n], acc[m][n]);
    }
  }

  const int jr = lr * 4;
#pragma unroll
  for (int m = 0; m < 4; ++m) {
#pragma unroll
    for (int n = 0; n < 4; ++n) {
      const int c    = n0 + wc + n * 16 + lc;   // < 512
      const float al = alpha[c], be = beta[c];
      const int head = c >> 6, kd = c & 63;
#pragma unroll
      for (int j = 0; j < 4; ++j) {
        const int r  = m0 + wr + m * 16 + jr + j;
        const int b  = r / 320;
        const int qr = r - b * 320;
        q_buf[((size_t)(b * 8 + head) * 320 + qr) * 64 + kd] = f2bf(acc[m][n][j] * al + be);
      }
    }
  }
}

// ---------------- attention ----------------
// Block = 64 q-rows (4 waves x 16), grid 1280 = 5 blocks/CU (R5's winning
// residency geometry; 320 = 5*64, no tail). KVBLK=32, 40 tiles. Swapped QK^T,
// in-reg P, K=16 PV, no-max exp2 softmax, bias as MFMA C-init.
// Ring-2 LDS (24KB), global_load_lds staging, counted vmcnt(1)+s_barrier.

__global__ __launch_bounds__(256) void attn_kernel(
    const u16* __restrict__ q_buf, const u16* __restrict__ kphys,
    const u16* __restrict__ vphys, const u16* __restrict__ bias_frag,
    u16* __restrict__ o_buf) {
  __shared__ __align__(16) u16 Kb[2][2048];
  __shared__ __align__(16) u16 Vb[2][4096];
  const int tid  = threadIdx.x;
  const int lane = tid & 63;
  const int w    = tid >> 6;
  const int lr   = lane >> 4, lc = lane & 15, jr = lr * 4;
  // XCD swizzle: 160 consecutive per XCD -> 32 (b,h) groups of 5 q-tiles
  const int g   = blockIdx.x;
  const int f   = (g & 7) * 160 + (g >> 3);
  const int qt  = f % 5;
  const int bh_ = f / 5;
  const int h = bh_ & 7, b = bh_ >> 3;
  const size_t bh = (size_t)bh_;
  const int q0 = qt * 64 + w * 16;

  bf16x8 bq0, bq1;
  {
    const u16* qp = q_buf + (bh * 320 + q0 + lc) * 64 + lr * 8;
    bq0 = *(const bf16x8*)(qp);
    bq1 = *(const bf16x8*)(qp + 32);
  }

  f32x4 oacc[8] = {};
  float lacc = 0.f;

  const u16* kt_base   = kphys + bh * (40 * 2048);
  const u16* vt_base   = vphys + bh * (40 * 4096);
  const u16* bias_base = bias_frag + (((size_t)(h * 5 + qt) * 40) * 256 + tid) * 8;

  u16x8 bbA, bbB;

  auto issue = [&](int buf, int kt) {
    async16(&Kb[buf][w * 512], kt_base + kt * 2048 + w * 512 + lane * 8);
    const u16* vs = vt_base + kt * 4096 + (w * 2) * 512 + lane * 8;
    async16(&Vb[buf][(w * 2) * 512], vs);
    async16(&Vb[buf][(w * 2 + 1) * 512], vs + 512);
  };
  auto gbias = [&](int kt, u16x8* dst) {
    *dst = *(const u16x8*)(bias_base + (size_t)kt * 2048);
  };

  auto compute = [&](int buf, const u16x8* bb) {
    const u16* Ksb = Kb[buf];
    const u16* Vsb = Vb[buf];
    const u16* bptr = (const u16*)bb;

    // S^T = K Q^T with bias as C-init; n in {0,1} key-chunks of 16
    f32x4 s[2];
    __builtin_amdgcn_s_setprio(1);
#pragma unroll
    for (int n = 0; n < 2; ++n) {
      const u16* kp = Ksb + (n * 16 + lc) * 64;
      const bf16x8 kf0 = *(const bf16x8*)(kp + ((lr ^ (lc & 7)) << 3));
      const bf16x8 kf1 = *(const bf16x8*)(kp + (((4 + lr) ^ (lc & 7)) << 3));
      f32x4 t;
#pragma unroll
      for (int j = 0; j < 4; ++j) t[j] = bf2f(bptr[n * 4 + j]);
      t = MFMA16(kf0, bq0, t);
      t = MFMA16(kf1, bq1, t);
      s[n] = t;
    }
    __builtin_amdgcn_s_setprio(0);

    // P = exp2(S') in-register; in-lane partial row-sum
    s16x4 pa[2];
    float ssum = 0.f;
#pragma unroll
    for (int n = 0; n < 2; ++n) {
      u16x4 pk;
#pragma unroll
      for (int j = 0; j < 4; ++j) {
        const float e = exp2f(s[n][j]);
        ssum += e;
        pk[j] = f2bf(e);
      }
      pa[n] = __builtin_bit_cast(s16x4, pk);
    }
    lacc += ssum;

    // PV: rotation (hc+(d>>1))&7 conflict-free
    __builtin_amdgcn_s_setprio(1);
#pragma unroll
    for (int nc = 0; nc < 8; ++nc) {
      const int d = nc * 16 + lc;
      const u16* vrow = Vsb + d * 32;
#pragma unroll
      for (int t = 0; t < 2; ++t) {
        const int ph = (t * 4 + lr + (d >> 1)) & 7;
        const s16x4 vf = __builtin_bit_cast(s16x4, *(const u16x4*)(vrow + ph * 4));
        oacc[nc] = MFMA16K16(pa[t], vf, oacc[nc]);
      }
    }
    __builtin_amdgcn_s_setprio(0);
  };

#define WAITBAR(N)                                                       \
  asm volatile("s_waitcnt vmcnt(" #N ") lgkmcnt(0)" ::: "memory");       \
  __builtin_amdgcn_s_barrier();

  issue(0, 0);
  gbias(0, &bbA);
  WAITBAR(1)   // tile0's 3 DMA done (bias0 may linger; compiler waits at use)

#pragma unroll 1
  for (int t = 0; t < 40; t += 2) {
    issue(1, t + 1);
    gbias(t + 1, &bbB);
    compute(0, &bbA);
    WAITBAR(1)
    if (t + 2 < 40) { issue(0, t + 2); gbias(t + 2, &bbA); }
    compute(1, &bbB);
    WAITBAR(1)
  }
#undef WAITBAR

  lacc += __shfl_xor(lacc, 16);
  lacc += __shfl_xor(lacc, 32);
  float invl[4];
#pragma unroll
  for (int j = 0; j < 4; ++j) invl[j] = 1.f / __shfl(lacc, jr + j);

#pragma unroll
  for (int nc = 0; nc < 8; ++nc)
#pragma unroll
    for (int j = 0; j < 4; ++j) {
      const float xv = oacc[nc][j] * invl[j];
      const float hs = xv * fminf(fmaxf(xv + 3.f, 0.f), 6.f) * (1.f / 6.f);
      o_buf[((size_t)b * 320 + q0 + jr + j) * 1024 + h * 128 + nc * 16 + lc] = f2bf(hs);
    }
}

// ---------------- GEMM 3: out = hswish(o) @ W_p^T, BN (f32 out) ----------------

__global__ __launch_bounds__(256) void gemm_p(
    const u16* __restrict__ O, const u16* __restrict__ Wt,
    const float* __restrict__ alpha, const float* __restrict__ beta,
    float* __restrict__ out) {
  __shared__ __align__(16) u16 As[128 * 64];
  __shared__ __align__(16) u16 Bs[128 * 64];
  const int tid  = threadIdx.x;
  const int lane = tid & 63;
  const int w    = tid >> 6;
  const int wr   = (w >> 1) * 64, wc = (w & 1) * 64;
  const int lr   = lane >> 4, lc = lane & 15;
  const int m0   = blockIdx.x * 128;
  const int n0   = blockIdx.y * 128;
  const int scol  = (lane & 7) * 8;
  f32x4 acc[4][4] = {};

  for (int kt = 0; kt < 1024; kt += 64) {
    if (kt) __syncthreads();
#pragma unroll
    for (int i = 0; i < 4; ++i) {
      const int row = w * 32 + i * 8 + (lane >> 3);
      async16(&As[(w * 32 + i * 8) * 64], O  + (size_t)(m0 + row) * 1024 + kt + scol);
      async16(&Bs[(w * 32 + i * 8) * 64], Wt + (size_t)(n0 + row) * 1024 + kt + scol);
    }
    __syncthreads();
#pragma unroll
    for (int kk = 0; kk < 2; ++kk) {
      bf16x8 af[4], bff[4];
#pragma unroll
      for (int m = 0; m < 4; ++m)
        af[m] = *(const bf16x8*)(&As[(wr + m * 16 + lc) * 64 + kk * 32 + lr * 8]);
#pragma unroll
      for (int n = 0; n < 4; ++n)
        bff[n] = *(const bf16x8*)(&Bs[(wc + n * 16 + lc) * 64 + kk * 32 + lr * 8]);
#pragma unroll
      for (int m = 0; m < 4; ++m)
#pragma unroll
        for (int n = 0; n < 4; ++n)
          acc[m][n] = MFMA16(af[m], bff[n], acc[m][n]);
    }
  }

  const int jr = lr * 4;
#pragma unroll
  for (int m = 0; m < 4; ++m) {
#pragma unroll
    for (int n = 0; n < 4; ++n) {
      const int c = n0 + wc + n * 16 + lc;   // < 384
      const float al = alpha[c], be = beta[c];
#pragma unroll
      for (int j = 0; j < 4; ++j) {
        const int r = m0 + wr + m * 16 + jr + j;
        out[(size_t)r * 384 + c] = acc[m][n][j] * al + be;
      }
    }
  }
}

// ---------------- launch ----------------

extern "C" void kernel_launch(void* const* d_in, const int* in_sizes, int n_in,
                              void* d_out, int out_size, void* d_ws, size_t ws_size,
                              hipStream_t stream) {
  const float* x      = (const float*)d_in[0];
  const float* W_kv   = (const float*)d_in[1];
  const float* g_kv   = (const float*)d_in[2];
  const float* b_kv   = (const float*)d_in[3];
  const float* rm_kv  = (const float*)d_in[4];
  const float* rv_kv  = (const float*)d_in[5];
  const float* W_q    = (const float*)d_in[6];
  const float* g_q    = (const float*)d_in[7];
  const float* b_q    = (const float*)d_in[8];
  const float* rm_q   = (const float*)d_in[9];
  const float* rv_q   = (const float*)d_in[10];
  const float* W_p    = (const float*)d_in[11];
  const float* g_p    = (const float*)d_in[12];
  const float* b_p    = (const float*)d_in[13];
  const float* rm_p   = (const float*)d_in[14];
  const float* rv_p   = (const float*)d_in[15];
  const float* attn_bias = (const float*)d_in[16];
  const int*   bias_idxs = (const int*)d_in[17];
  const int n_off = in_sizes[16] / 8;

  char* ws = (char*)d_ws;
  size_t off = 0;
  auto alloc = [&](size_t bytes) -> void* {
    void* p = ws + off;
    off += (bytes + 255) & ~(size_t)255;
    return p;
  };
  u16* x_bf    = (u16*)alloc((size_t)40960 * 256 * 2);
  u16* wkv_bf  = (u16*)alloc((size_t)1536 * 256 * 2);
  u16* wq_bf   = (u16*)alloc((size_t)512 * 256 * 2);
  u16* wp_bf   = (u16*)alloc((size_t)384 * 1024 * 2);
  float* al_kv = (float*)alloc(1536 * 4);
  float* be_kv = (float*)alloc(1536 * 4);
  float* al_q  = (float*)alloc(512 * 4);
  float* be_q  = (float*)alloc(512 * 4);
  float* al_p  = (float*)alloc(384 * 4);
  float* be_p  = (float*)alloc(384 * 4);
  u16* k_buf   = (u16*)alloc((size_t)256 * 40 * 2048 * 2);
  u16* vt_buf  = (u16*)alloc((size_t)256 * 40 * 4096 * 2);
  u16* q_buf   = (u16*)alloc((size_t)32 * 8 * 320 * 64 * 2);
  u16* bias_fr = (u16*)alloc((size_t)8 * 5 * 40 * 256 * 8 * 2);
  u16* o_buf   = (u16*)alloc((size_t)32 * 320 * 1024 * 2);
  (void)ws_size; (void)n_in; (void)out_size;

  cvt_f32_bf16<<<(2621440 + 255) / 256, 256, 0, stream>>>(x, x_bf, 2621440);
  cvt_f32_bf16<<<(98304 + 255) / 256, 256, 0, stream>>>(W_kv, wkv_bf, 98304);
  cvt_f32_bf16<<<(32768 + 255) / 256, 256, 0, stream>>>(W_q, wq_bf, 32768);
  cvt_f32_bf16<<<(98304 + 255) / 256, 256, 0, stream>>>(W_p, wp_bf, 98304);
  bn_prep<<<6, 256, 0, stream>>>(g_kv, b_kv, rm_kv, rv_kv, al_kv, be_kv, 1536, 1.0f);
  bn_prep<<<2, 256, 0, stream>>>(g_q, b_q, rm_q, rv_q, al_q, be_q, 512, 0.125f * LOG2E);
  bn_prep<<<2, 256, 0, stream>>>(g_p, b_p, rm_p, rv_p, al_p, be_p, 384, 1.0f);
  bias_expand_frag<<<(3276800 + 255) / 256, 256, 0, stream>>>(attn_bias, bias_idxs, bias_fr, n_off);

  gemm_kv<<<dim3(320, 12), 256, 0, stream>>>(x_bf, wkv_bf, al_kv, be_kv, k_buf, vt_buf);
  gemm_q<<<dim3(80, 4), 256, 0, stream>>>(x_bf, wq_bf, al_q, be_q, q_buf);
  attn_kernel<<<dim3(1280), 256, 0, stream>>>(q_buf, k_buf, vt_buf, bias_fr, o_buf);
  gemm_p<<<dim3(80, 3), 256, 0, stream>>>(o_buf, wp_bf, al_p, be_p, (float*)d_out);
}

// Round 11
// 206.819 us; speedup vs baseline: 1.1662x; 1.0088x over previous
//
#include <hip/hip_runtime.h>
#include <hip/hip_bf16.h>
#include <cstdint>
#include <cstddef>

typedef unsigned short u16;
typedef __bf16 bf16x8 __attribute__((ext_vector_type(8)));
typedef float  f32x4  __attribute__((ext_vector_type(4)));
typedef u16    u16x8  __attribute__((ext_vector_type(8)));
typedef u16    u16x4  __attribute__((ext_vector_type(4)));
typedef short  s16x4  __attribute__((ext_vector_type(4)));

#define MFMA16(A_, B_, C_) __builtin_amdgcn_mfma_f32_16x16x32_bf16((A_), (B_), (C_), 0, 0, 0)
#define MFMA16K16(A_, B_, C_) __builtin_amdgcn_mfma_f32_16x16x16bf16_1k((A_), (B_), (C_), 0, 0, 0)

#define LOG2E 1.4426950408889634f

__device__ __forceinline__ u16 f2bf(float f) {
  return __builtin_bit_cast(u16, (__bf16)f);
}

// async global->LDS, 16B per lane. lds must be wave-uniform base; HW adds lane*16.
__device__ __forceinline__ void async16(u16* lds, const u16* g) {
  __builtin_amdgcn_global_load_lds(
      (const __attribute__((address_space(1))) unsigned int*)g,
      (__attribute__((address_space(3))) unsigned int*)lds, 16, 0, 0);
}

// ---------------- prep kernels ----------------

__global__ void cvt_f32_bf16(const float* __restrict__ src, u16* __restrict__ dst, int n4) {
  int i = blockIdx.x * 256 + threadIdx.x;
  if (i < n4) {
    const float4 v = ((const float4*)src)[i];
    u16x4 o;
    o[0] = f2bf(v.x); o[1] = f2bf(v.y); o[2] = f2bf(v.z); o[3] = f2bf(v.w);
    ((u16x4*)dst)[i] = o;
  }
}

__device__ __forceinline__ void cvt4(const float* src, u16* dst, int i) {
  const float4 v = ((const float4*)src)[i];
  u16x4 o;
  o[0] = f2bf(v.x); o[1] = f2bf(v.y); o[2] = f2bf(v.z); o[3] = f2bf(v.w);
  ((u16x4*)dst)[i] = o;
}

__device__ __forceinline__ void bn1(const float* g, const float* b, const float* rm,
                                    const float* rv, float* alpha, float* beta,
                                    int i, float scale) {
  float a0 = g[i] * rsqrtf(rv[i] + 1e-5f);
  alpha[i] = a0 * scale;
  beta[i]  = (b[i] - rm[i] * a0) * scale;
}

// all small prep in one dispatch: 3 weight cvts + 3 bn folds
__global__ void prep_fused(
    const float* __restrict__ Wkv, const float* __restrict__ Wq, const float* __restrict__ Wp,
    u16* __restrict__ wkv_bf, u16* __restrict__ wq_bf, u16* __restrict__ wp_bf,
    const float* __restrict__ g_kv, const float* __restrict__ b_kv,
    const float* __restrict__ rm_kv, const float* __restrict__ rv_kv,
    float* __restrict__ al_kv, float* __restrict__ be_kv,
    const float* __restrict__ g_q, const float* __restrict__ b_q,
    const float* __restrict__ rm_q, const float* __restrict__ rv_q,
    float* __restrict__ al_q, float* __restrict__ be_q,
    const float* __restrict__ g_p, const float* __restrict__ b_p,
    const float* __restrict__ rm_p, const float* __restrict__ rv_p,
    float* __restrict__ al_p, float* __restrict__ be_p) {
  const int bid = blockIdx.x, t = threadIdx.x;
  if (bid < 384) {
    cvt4(Wkv, wkv_bf, bid * 256 + t);                       // 98304 f4
  } else if (bid < 512) {
    cvt4(Wq, wq_bf, (bid - 384) * 256 + t);                 // 32768 f4
  } else if (bid < 896) {
    cvt4(Wp, wp_bf, (bid - 512) * 256 + t);                 // 98304 f4
  } else if (bid < 902) {
    bn1(g_kv, b_kv, rm_kv, rv_kv, al_kv, be_kv, (bid - 896) * 256 + t, 1.0f);
  } else if (bid < 904) {
    bn1(g_q, b_q, rm_q, rv_q, al_q, be_q, (bid - 902) * 256 + t, 0.125f * LOG2E);
  } else {
    const int i = (bid - 904) * 256 + t;
    if (i < 384) bn1(g_p, b_p, rm_p, rv_p, al_p, be_p, i, 1.0f);
  }
}

// bias (x log2e, f32) in PV-fragment order: [h][qt5][kt40][tid256][nn2*j4]
__global__ void bias_expand_frag(const float* __restrict__ attn_bias, const int* __restrict__ idxs,
                                 float* __restrict__ bias_frag, int n_off) {
  int i = blockIdx.x * 256 + threadIdx.x;
  if (i >= 8 * 5 * 40 * 256 * 8) return;
  const int e8  = i & 7;
  const int nn  = e8 >> 2;
  const int j   = e8 & 3;
  const int tid = (i >> 3) & 255;
  int v = i >> 11;          // (h*5+qt)*40 + kt
  const int kt = v % 40; v /= 40;
  const int qt = v % 5;
  const int h  = v / 5;
  const int w = tid >> 6, lr = (tid >> 4) & 3, lc = tid & 15;
  const int q = qt * 64 + w * 16 + lc;
  const int k = kt * 32 + nn * 16 + lr * 4 + j;
  bias_frag[i] = attn_bias[h * n_off + idxs[q * 1280 + k]] * LOG2E;
}

// ---------------- GEMM 1: kv = x @ W_kv^T, BN, scatter to K-phys / V-phys ----------------
// Per (bh, kt32): K = 32 rows x 64ch, 16B chunk c at c^(r&7)            (b128 reads)
// V = 128 d-rows x 32 keys (64B), 8B chunk hc at (hc+(d>>1))&7          (b64 reads, conflict-free)

__global__ __launch_bounds__(256) void gemm_kv(
    const u16* __restrict__ A, const u16* __restrict__ Wt,
    const float* __restrict__ alpha, const float* __restrict__ beta,
    u16* __restrict__ k_buf, u16* __restrict__ vt_buf) {
  __shared__ __align__(16) u16 As[128 * 64];
  __shared__ __align__(16) u16 Bs[128 * 64];
  const int tid  = threadIdx.x;
  const int lane = tid & 63;
  const int w    = tid >> 6;
  const int wr   = (w >> 1) * 64, wc = (w & 1) * 64;
  const int lr   = lane >> 4, lc = lane & 15;
  const int m0   = blockIdx.x * 128;
  const int n0   = blockIdx.y * 128;
  const int scol  = (lane & 7) * 8;
  f32x4 acc[4][4] = {};

  for (int kt = 0; kt < 256; kt += 64) {
    if (kt) __syncthreads();
#pragma unroll
    for (int i = 0; i < 4; ++i) {
      const int row = w * 32 + i * 8 + (lane >> 3);
      async16(&As[(w * 32 + i * 8) * 64], A  + (size_t)(m0 + row) * 256 + kt + scol);
      async16(&Bs[(w * 32 + i * 8) * 64], Wt + (size_t)(n0 + row) * 256 + kt + scol);
    }
    __syncthreads();
#pragma unroll
    for (int kk = 0; kk < 2; ++kk) {
      bf16x8 af[4], bff[4];
#pragma unroll
      for (int m = 0; m < 4; ++m)
        af[m] = *(const bf16x8*)(&As[(wr + m * 16 + lc) * 64 + kk * 32 + lr * 8]);
#pragma unroll
      for (int n = 0; n < 4; ++n)
        bff[n] = *(const bf16x8*)(&Bs[(wc + n * 16 + lc) * 64 + kk * 32 + lr * 8]);
#pragma unroll
      for (int m = 0; m < 4; ++m)
#pragma unroll
        for (int n = 0; n < 4; ++n)
          acc[m][n] = MFMA16(af[m], bff[n], acc[m][n]);
    }
  }

  const int jr = lr * 4;
#pragma unroll
  for (int m = 0; m < 4; ++m) {
    const int r0  = m0 + wr + m * 16 + jr;
    const int b   = r0 / 1280;
    const int np0 = r0 - b * 1280;          // global key, 4-aligned
    const int kt  = np0 >> 5;
    const int kl  = np0 & 31;               // key-in-tile, 4-aligned
#pragma unroll
    for (int n = 0; n < 4; ++n) {
      const int c    = n0 + wc + n * 16 + lc;
      const float al = alpha[c], be = beta[c];
      const int head = c / 192;
      const int off  = c - head * 192;
      const size_t bh = (size_t)(b * 8 + head);
      if (off < 64) {
        const size_t base = ((bh * 40 + kt) << 11);
#pragma unroll
        for (int j = 0; j < 4; ++j) {
          const int r = kl + j;
          k_buf[base + (r << 6) + ((((off >> 3) ^ (r & 7)) << 3)) + (off & 7)] =
              f2bf(acc[m][n][j] * al + be);
        }
      } else {
        const int d = off - 64;
        u16x4 pk;
#pragma unroll
        for (int j = 0; j < 4; ++j) pk[j] = f2bf(acc[m][n][j] * al + be);
        const size_t dst = ((size_t)(bh * 40 + kt) << 12) + d * 32 +
                           ((((kl >> 2) + (d >> 1)) & 7) << 2);
        *(u16x4*)(&vt_buf[dst]) = pk;
      }
    }
  }
}

// ---------------- GEMM 2: q = subsample(x) @ W_q^T, BN, *(0.125*log2e folded) ----------------

__device__ __forceinline__ int sub_src_row(int qr) {
  if (qr < 256) return ((qr >> 4) * 64) + ((qr & 15) * 2);
  int rr = qr - 256;
  return 1024 + ((rr >> 3) * 32) + ((rr & 7) * 2);
}

__global__ __launch_bounds__(256) void gemm_q(
    const u16* __restrict__ X, const u16* __restrict__ Wt,
    const float* __restrict__ alpha, const float* __restrict__ beta,
    u16* __restrict__ q_buf) {
  __shared__ __align__(16) u16 As[128 * 64];
  __shared__ __align__(16) u16 Bs[128 * 64];
  const int tid  = threadIdx.x;
  const int lane = tid & 63;
  const int w    = tid >> 6;
  const int wr   = (w >> 1) * 64, wc = (w & 1) * 64;
  const int lr   = lane >> 4, lc = lane & 15;
  const int m0   = blockIdx.x * 128;
  const int n0   = blockIdx.y * 128;
  const int scol  = (lane & 7) * 8;
  f32x4 acc[4][4] = {};

  for (int kt = 0; kt < 256; kt += 64) {
    if (kt) __syncthreads();
#pragma unroll
    for (int i = 0; i < 4; ++i) {
      const int row = w * 32 + i * 8 + (lane >> 3);
      const int gr  = m0 + row;
      const int bb  = gr / 320;
      const int qr  = gr - bb * 320;
      async16(&As[(w * 32 + i * 8) * 64],
              X + (size_t)(bb * 1280 + sub_src_row(qr)) * 256 + kt + scol);
      async16(&Bs[(w * 32 + i * 8) * 64], Wt + (size_t)(n0 + row) * 256 + kt + scol);
    }
    __syncthreads();
#pragma unroll
    for (int kk = 0; kk < 2; ++kk) {
      bf16x8 af[4], bff[4];
#pragma unroll
      for (int m = 0; m < 4; ++m)
        af[m] = *(const bf16x8*)(&As[(wr + m * 16 + lc) * 64 + kk * 32 + lr * 8]);
#pragma unroll
      for (int n = 0; n < 4; ++n)
        bff[n] = *(const bf16x8*)(&Bs[(wc + n * 16 + lc) * 64 + kk * 32 + lr * 8]);
#pragma unroll
      for (int m = 0; m < 4; ++m)
#pragma unroll
        for (int n = 0; n < 4; ++n)
          acc[m][n] = MFMA16(af[m], bff[n], acc[m][n]);
    }
  }

  const int jr = lr * 4;
#pragma unroll
  for (int m = 0; m < 4; ++m) {
#pragma unroll
    for (int n = 0; n < 4; ++n) {
      const int c    = n0 + wc + n * 16 + lc;   // < 512
      const float al = alpha[c], be = beta[c];
      const int head = c >> 6, kd = c & 63;
#pragma unroll
      for (int j = 0; j < 4; ++j) {
        const int r  = m0 + wr + m * 16 + jr + j;
        const int b  = r / 320;
        const int qr = r - b * 320;
        q_buf[((size_t)(b * 8 + head) * 320 + qr) * 64 + kd] = f2bf(acc[m][n][j] * al + be);
      }
    }
  }
}

// ---------------- attention ----------------
// Block = 64 q-rows (4 waves x 16), grid 1280 = 5 blocks/CU. KVBLK=32, 40 tiles.
// Swapped QK^T, in-reg P, K=16 PV, no-max exp2 softmax, f32 bias as MFMA C-init.
// Ring-2 LDS (24KB), global_load_lds staging, counted vmcnt(2)+s_barrier.
// VALU trims: f32 bias (no cvt), hoisted LDS offsets (ph independent of nc:
// (t*4+lr+(d>>1))&7 == (t*4+lr+(lc>>1))&7 since d=nc*16+lc and nc*8 mod 8 == 0).

__global__ __launch_bounds__(256) void attn_kernel(
    const u16* __restrict__ q_buf, const u16* __restrict__ kphys,
    const u16* __restrict__ vphys, const float* __restrict__ bias_frag,
    u16* __restrict__ o_buf) {
  __shared__ __align__(16) u16 Kb[2][2048];
  __shared__ __align__(16) u16 Vb[2][4096];
  const int tid  = threadIdx.x;
  const int lane = tid & 63;
  const int w    = tid >> 6;
  const int lr   = lane >> 4, lc = lane & 15, jr = lr * 4;
  // XCD swizzle: 160 consecutive per XCD -> 32 (b,h) groups of 5 q-tiles
  const int g   = blockIdx.x;
  const int f   = (g & 7) * 160 + (g >> 3);
  const int qt  = f % 5;
  const int bh_ = f / 5;
  const int h = bh_ & 7, b = bh_ >> 3;
  const size_t bh = (size_t)bh_;
  const int q0 = qt * 64 + w * 16;

  bf16x8 bq0, bq1;
  {
    const u16* qp = q_buf + (bh * 320 + q0 + lc) * 64 + lr * 8;
    bq0 = *(const bf16x8*)(qp);
    bq1 = *(const bf16x8*)(qp + 32);
  }

  f32x4 oacc[8] = {};
  float lacc = 0.f;

  const u16* kt_base     = kphys + bh * (40 * 2048);
  const u16* vt_base     = vphys + bh * (40 * 4096);
  const float* bias_base = bias_frag + ((size_t)(h * 5 + qt) * 40) * 2048 + tid * 8;

  // hoisted lane-constant LDS offsets (u16 elements)
  const int ko0 = lc * 64 + ((lr ^ (lc & 7)) << 3);
  const int ko1 = lc * 64 + (((4 + lr) ^ (lc & 7)) << 3);
  const int po0 = lc * 32 + ((lr + (lc >> 1)) & 7) * 4;
  const int po1 = lc * 32 + ((4 + lr + (lc >> 1)) & 7) * 4;

  f32x4 bbA[2], bbB[2];

  auto issue = [&](int buf, int kt) {
    async16(&Kb[buf][w * 512], kt_base + kt * 2048 + w * 512 + lane * 8);
    const u16* vs = vt_base + kt * 4096 + (w * 2) * 512 + lane * 8;
    async16(&Vb[buf][(w * 2) * 512], vs);
    async16(&Vb[buf][(w * 2 + 1) * 512], vs + 512);
  };
  auto gbias = [&](int kt, f32x4* dst) {
    const float* bp = bias_base + (size_t)kt * 2048;
    dst[0] = *(const f32x4*)(bp);
    dst[1] = *(const f32x4*)(bp + 4);
  };

  auto compute = [&](int buf, const f32x4* bb) {
    const u16* Ksb = Kb[buf];
    const u16* Vsb = Vb[buf];

    // S^T = K Q^T with f32 bias as C-init; n in {0,1} key-chunks of 16
    f32x4 s[2];
    __builtin_amdgcn_s_setprio(1);
#pragma unroll
    for (int n = 0; n < 2; ++n) {
      const bf16x8 kf0 = *(const bf16x8*)(Ksb + n * 1024 + ko0);
      const bf16x8 kf1 = *(const bf16x8*)(Ksb + n * 1024 + ko1);
      f32x4 t = bb[n];
      t = MFMA16(kf0, bq0, t);
      t = MFMA16(kf1, bq1, t);
      s[n] = t;
    }
    __builtin_amdgcn_s_setprio(0);

    // P = exp2(S') in-register; in-lane partial row-sum
    s16x4 pa[2];
    float ssum = 0.f;
#pragma unroll
    for (int n = 0; n < 2; ++n) {
      u16x4 pk;
#pragma unroll
      for (int j = 0; j < 4; ++j) {
        const float e = exp2f(s[n][j]);
        ssum += e;
        pk[j] = f2bf(e);
      }
      pa[n] = __builtin_bit_cast(s16x4, pk);
    }
    lacc += ssum;

    // PV: addresses = 2 lane regs + compile-time immediates; conflict-free
    __builtin_amdgcn_s_setprio(1);
#pragma unroll
    for (int nc = 0; nc < 8; ++nc) {
      const u16* vrow = Vsb + nc * 512;
      const s16x4 vf0 = __builtin_bit_cast(s16x4, *(const u16x4*)(vrow + po0));
      const s16x4 vf1 = __builtin_bit_cast(s16x4, *(const u16x4*)(vrow + po1));
      oacc[nc] = MFMA16K16(pa[0], vf0, oacc[nc]);
      oacc[nc] = MFMA16K16(pa[1], vf1, oacc[nc]);
    }
    __builtin_amdgcn_s_setprio(0);
  };

#define WAITBAR(N)                                                       \
  asm volatile("s_waitcnt vmcnt(" #N ") lgkmcnt(0)" ::: "memory");       \
  __builtin_amdgcn_s_barrier();

  issue(0, 0);
  gbias(0, bbA);
  WAITBAR(2)   // tile0's 3 DMA done; bias0's 2 loads may linger (waited at use)

#pragma unroll 1
  for (int t = 0; t < 40; t += 2) {
    issue(1, t + 1);
    gbias(t + 1, bbB);
    compute(0, bbA);
    WAITBAR(2)
    if (t + 2 < 40) { issue(0, t + 2); gbias(t + 2, bbA); }
    compute(1, bbB);
    WAITBAR(2)
  }
#undef WAITBAR

  lacc += __shfl_xor(lacc, 16);
  lacc += __shfl_xor(lacc, 32);
  float invl[4];
#pragma unroll
  for (int j = 0; j < 4; ++j) invl[j] = 1.f / __shfl(lacc, jr + j);

#pragma unroll
  for (int nc = 0; nc < 8; ++nc)
#pragma unroll
    for (int j = 0; j < 4; ++j) {
      const float xv = oacc[nc][j] * invl[j];
      const float hs = xv * fminf(fmaxf(xv + 3.f, 0.f), 6.f) * (1.f / 6.f);
      o_buf[((size_t)b * 320 + q0 + jr + j) * 1024 + h * 128 + nc * 16 + lc] = f2bf(hs);
    }
}

// ---------------- GEMM 3: out = hswish(o) @ W_p^T, BN (f32 out) ----------------

__global__ __launch_bounds__(256) void gemm_p(
    const u16* __restrict__ O, const u16* __restrict__ Wt,
    const float* __restrict__ alpha, const float* __restrict__ beta,
    float* __restrict__ out) {
  __shared__ __align__(16) u16 As[128 * 64];
  __shared__ __align__(16) u16 Bs[128 * 64];
  const int tid  = threadIdx.x;
  const int lane = tid & 63;
  const int w    = tid >> 6;
  const int wr   = (w >> 1) * 64, wc = (w & 1) * 64;
  const int lr   = lane >> 4, lc = lane & 15;
  const int m0   = blockIdx.x * 128;
  const int n0   = blockIdx.y * 128;
  const int scol  = (lane & 7) * 8;
  f32x4 acc[4][4] = {};

  for (int kt = 0; kt < 1024; kt += 64) {
    if (kt) __syncthreads();
#pragma unroll
    for (int i = 0; i < 4; ++i) {
      const int row = w * 32 + i * 8 + (lane >> 3);
      async16(&As[(w * 32 + i * 8) * 64], O  + (size_t)(m0 + row) * 1024 + kt + scol);
      async16(&Bs[(w * 32 + i * 8) * 64], Wt + (size_t)(n0 + row) * 1024 + kt + scol);
    }
    __syncthreads();
#pragma unroll
    for (int kk = 0; kk < 2; ++kk) {
      bf16x8 af[4], bff[4];
#pragma unroll
      for (int m = 0; m < 4; ++m)
        af[m] = *(const bf16x8*)(&As[(wr + m * 16 + lc) * 64 + kk * 32 + lr * 8]);
#pragma unroll
      for (int n = 0; n < 4; ++n)
        bff[n] = *(const bf16x8*)(&Bs[(wc + n * 16 + lc) * 64 + kk * 32 + lr * 8]);
#pragma unroll
      for (int m = 0; m < 4; ++m)
#pragma unroll
        for (int n = 0; n < 4; ++n)
          acc[m][n] = MFMA16(af[m], bff[n], acc[m][n]);
    }
  }

  const int jr = lr * 4;
#pragma unroll
  for (int m = 0; m < 4; ++m) {
#pragma unroll
    for (int n = 0; n < 4; ++n) {
      const int c = n0 + wc + n * 16 + lc;   // < 384
      const float al = alpha[c], be = beta[c];
#pragma unroll
      for (int j = 0; j < 4; ++j) {
        const int r = m0 + wr + m * 16 + jr + j;
        out[(size_t)r * 384 + c] = acc[m][n][j] * al + be;
      }
    }
  }
}

// ---------------- launch ----------------

extern "C" void kernel_launch(void* const* d_in, const int* in_sizes, int n_in,
                              void* d_out, int out_size, void* d_ws, size_t ws_size,
                              hipStream_t stream) {
  const float* x      = (const float*)d_in[0];
  const float* W_kv   = (const float*)d_in[1];
  const float* g_kv   = (const float*)d_in[2];
  const float* b_kv   = (const float*)d_in[3];
  const float* rm_kv  = (const float*)d_in[4];
  const float* rv_kv  = (const float*)d_in[5];
  const float* W_q    = (const float*)d_in[6];
  const float* g_q    = (const float*)d_in[7];
  const float* b_q    = (const float*)d_in[8];
  const float* rm_q   = (const float*)d_in[9];
  const float* rv_q   = (const float*)d_in[10];
  const float* W_p    = (const float*)d_in[11];
  const float* g_p    = (const float*)d_in[12];
  const float* b_p    = (const float*)d_in[13];
  const float* rm_p   = (const float*)d_in[14];
  const float* rv_p   = (const float*)d_in[15];
  const float* attn_bias = (const float*)d_in[16];
  const int*   bias_idxs = (const int*)d_in[17];
  const int n_off = in_sizes[16] / 8;

  char* ws = (char*)d_ws;
  size_t off = 0;
  auto alloc = [&](size_t bytes) -> void* {
    void* p = ws + off;
    off += (bytes + 255) & ~(size_t)255;
    return p;
  };
  u16* x_bf    = (u16*)alloc((size_t)40960 * 256 * 2);
  u16* wkv_bf  = (u16*)alloc((size_t)1536 * 256 * 2);
  u16* wq_bf   = (u16*)alloc((size_t)512 * 256 * 2);
  u16* wp_bf   = (u16*)alloc((size_t)384 * 1024 * 2);
  float* al_kv = (float*)alloc(1536 * 4);
  float* be_kv = (float*)alloc(1536 * 4);
  float* al_q  = (float*)alloc(512 * 4);
  float* be_q  = (float*)alloc(512 * 4);
  float* al_p  = (float*)alloc(384 * 4);
  float* be_p  = (float*)alloc(384 * 4);
  u16* k_buf   = (u16*)alloc((size_t)256 * 40 * 2048 * 2);
  u16* vt_buf  = (u16*)alloc((size_t)256 * 40 * 4096 * 2);
  u16* q_buf   = (u16*)alloc((size_t)32 * 8 * 320 * 64 * 2);
  float* bias_fr = (float*)alloc((size_t)8 * 5 * 40 * 256 * 8 * 4);
  u16* o_buf   = (u16*)alloc((size_t)32 * 320 * 1024 * 2);
  (void)ws_size; (void)n_in; (void)out_size;

  cvt_f32_bf16<<<(2621440 + 255) / 256, 256, 0, stream>>>(x, x_bf, 2621440);
  prep_fused<<<906, 256, 0, stream>>>(
      W_kv, W_q, W_p, wkv_bf, wq_bf, wp_bf,
      g_kv, b_kv, rm_kv, rv_kv, al_kv, be_kv,
      g_q, b_q, rm_q, rv_q, al_q, be_q,
      g_p, b_p, rm_p, rv_p, al_p, be_p);
  bias_expand_frag<<<(3276800 + 255) / 256, 256, 0, stream>>>(attn_bias, bias_idxs, bias_fr, n_off);

  gemm_kv<<<dim3(320, 12), 256, 0, stream>>>(x_bf, wkv_bf, al_kv, be_kv, k_buf, vt_buf);
  gemm_q<<<dim3(80, 4), 256, 0, stream>>>(x_bf, wq_bf, al_q, be_q, q_buf);
  attn_kernel<<<dim3(1280), 256, 0, stream>>>(q_buf, k_buf, vt_buf, bias_fr, o_buf);
  gemm_p<<<dim3(80, 3), 256, 0, stream>>>(o_buf, wp_bf, al_p, be_p, (float*)d_out);
}

// Round 12
// 193.615 us; speedup vs baseline: 1.2458x; 1.0682x over previous
//
#include <hip/hip_runtime.h>
#include <hip/hip_bf16.h>
#include <cstdint>
#include <cstddef>

typedef unsigned short u16;
typedef __bf16 bf16x8 __attribute__((ext_vector_type(8)));
typedef float  f32x4  __attribute__((ext_vector_type(4)));
typedef u16    u16x8  __attribute__((ext_vector_type(8)));
typedef u16    u16x4  __attribute__((ext_vector_type(4)));
typedef short  s16x4  __attribute__((ext_vector_type(4)));

#define MFMA16(A_, B_, C_) __builtin_amdgcn_mfma_f32_16x16x32_bf16((A_), (B_), (C_), 0, 0, 0)
#define MFMA16K16(A_, B_, C_) __builtin_amdgcn_mfma_f32_16x16x16bf16_1k((A_), (B_), (C_), 0, 0, 0)

#define LOG2E 1.4426950408889634f

#if __has_builtin(__builtin_amdgcn_exp2f)
#define EXP2(x) __builtin_amdgcn_exp2f(x)
#else
#define EXP2(x) exp2f(x)
#endif

__device__ __forceinline__ u16 f2bf(float f) {
  return __builtin_bit_cast(u16, (__bf16)f);
}
__device__ __forceinline__ float bf2f(u16 v) {
  return (float)__builtin_bit_cast(__bf16, v);
}

// async global->LDS, 16B per lane. lds must be wave-uniform base; HW adds lane*16.
__device__ __forceinline__ void async16(u16* lds, const u16* g) {
  __builtin_amdgcn_global_load_lds(
      (const __attribute__((address_space(1))) unsigned int*)g,
      (__attribute__((address_space(3))) unsigned int*)lds, 16, 0, 0);
}

// ---------------- prep kernels ----------------

__global__ void cvt_f32_bf16(const float* __restrict__ src, u16* __restrict__ dst, int n4) {
  int i = blockIdx.x * 256 + threadIdx.x;
  if (i < n4) {
    const float4 v = ((const float4*)src)[i];
    u16x4 o;
    o[0] = f2bf(v.x); o[1] = f2bf(v.y); o[2] = f2bf(v.z); o[3] = f2bf(v.w);
    ((u16x4*)dst)[i] = o;
  }
}

__device__ __forceinline__ void cvt4(const float* src, u16* dst, int i) {
  const float4 v = ((const float4*)src)[i];
  u16x4 o;
  o[0] = f2bf(v.x); o[1] = f2bf(v.y); o[2] = f2bf(v.z); o[3] = f2bf(v.w);
  ((u16x4*)dst)[i] = o;
}

__device__ __forceinline__ void bn1(const float* g, const float* b, const float* rm,
                                    const float* rv, float* alpha, float* beta,
                                    int i, float scale) {
  float a0 = g[i] * rsqrtf(rv[i] + 1e-5f);
  alpha[i] = a0 * scale;
  beta[i]  = (b[i] - rm[i] * a0) * scale;
}

// all small prep in one dispatch: 3 weight cvts + 3 bn folds
__global__ void prep_fused(
    const float* __restrict__ Wkv, const float* __restrict__ Wq, const float* __restrict__ Wp,
    u16* __restrict__ wkv_bf, u16* __restrict__ wq_bf, u16* __restrict__ wp_bf,
    const float* __restrict__ g_kv, const float* __restrict__ b_kv,
    const float* __restrict__ rm_kv, const float* __restrict__ rv_kv,
    float* __restrict__ al_kv, float* __restrict__ be_kv,
    const float* __restrict__ g_q, const float* __restrict__ b_q,
    const float* __restrict__ rm_q, const float* __restrict__ rv_q,
    float* __restrict__ al_q, float* __restrict__ be_q,
    const float* __restrict__ g_p, const float* __restrict__ b_p,
    const float* __restrict__ rm_p, const float* __restrict__ rv_p,
    float* __restrict__ al_p, float* __restrict__ be_p) {
  const int bid = blockIdx.x, t = threadIdx.x;
  if (bid < 384) {
    cvt4(Wkv, wkv_bf, bid * 256 + t);                       // 98304 f4
  } else if (bid < 512) {
    cvt4(Wq, wq_bf, (bid - 384) * 256 + t);                 // 32768 f4
  } else if (bid < 896) {
    cvt4(Wp, wp_bf, (bid - 512) * 256 + t);                 // 98304 f4
  } else if (bid < 902) {
    bn1(g_kv, b_kv, rm_kv, rv_kv, al_kv, be_kv, (bid - 896) * 256 + t, 1.0f);
  } else if (bid < 904) {
    bn1(g_q, b_q, rm_q, rv_q, al_q, be_q, (bid - 902) * 256 + t, 0.125f * LOG2E);
  } else {
    const int i = (bid - 904) * 256 + t;
    if (i < 384) bn1(g_p, b_p, rm_p, rv_p, al_p, be_p, i, 1.0f);
  }
}

// bias (x log2e, bf16) in PV-fragment order: [h][qt5][kt40][tid256][nn2*j4]
__global__ void bias_expand_frag(const float* __restrict__ attn_bias, const int* __restrict__ idxs,
                                 u16* __restrict__ bias_frag, int n_off) {
  int i = blockIdx.x * 256 + threadIdx.x;
  if (i >= 8 * 5 * 40 * 256 * 8) return;
  const int e8  = i & 7;
  const int nn  = e8 >> 2;
  const int j   = e8 & 3;
  const int tid = (i >> 3) & 255;
  int v = i >> 11;          // (h*5+qt)*40 + kt
  const int kt = v % 40; v /= 40;
  const int qt = v % 5;
  const int h  = v / 5;
  const int w = tid >> 6, lr = (tid >> 4) & 3, lc = tid & 15;
  const int q = qt * 64 + w * 16 + lc;
  const int k = kt * 32 + nn * 16 + lr * 4 + j;
  bias_frag[i] = f2bf(attn_bias[h * n_off + idxs[q * 1280 + k]] * LOG2E);
}

// ---------------- GEMM 1: kv = x @ W_kv^T, BN, scatter to K-phys / V-phys ----------------
// Per (bh, kt32): K = 32 rows x 64ch, 16B chunk c at c^(r&7)            (b128 reads)
// V = 128 d-rows x 32 keys (64B), 8B chunk hc at (hc+(d>>1))&7          (b64 reads, conflict-free)

__global__ __launch_bounds__(256) void gemm_kv(
    const u16* __restrict__ A, const u16* __restrict__ Wt,
    const float* __restrict__ alpha, const float* __restrict__ beta,
    u16* __restrict__ k_buf, u16* __restrict__ vt_buf) {
  __shared__ __align__(16) u16 As[128 * 64];
  __shared__ __align__(16) u16 Bs[128 * 64];
  const int tid  = threadIdx.x;
  const int lane = tid & 63;
  const int w    = tid >> 6;
  const int wr   = (w >> 1) * 64, wc = (w & 1) * 64;
  const int lr   = lane >> 4, lc = lane & 15;
  const int m0   = blockIdx.x * 128;
  const int n0   = blockIdx.y * 128;
  const int scol  = (lane & 7) * 8;
  f32x4 acc[4][4] = {};

  for (int kt = 0; kt < 256; kt += 64) {
    if (kt) __syncthreads();
#pragma unroll
    for (int i = 0; i < 4; ++i) {
      const int row = w * 32 + i * 8 + (lane >> 3);
      async16(&As[(w * 32 + i * 8) * 64], A  + (size_t)(m0 + row) * 256 + kt + scol);
      async16(&Bs[(w * 32 + i * 8) * 64], Wt + (size_t)(n0 + row) * 256 + kt + scol);
    }
    __syncthreads();
#pragma unroll
    for (int kk = 0; kk < 2; ++kk) {
      bf16x8 af[4], bff[4];
#pragma unroll
      for (int m = 0; m < 4; ++m)
        af[m] = *(const bf16x8*)(&As[(wr + m * 16 + lc) * 64 + kk * 32 + lr * 8]);
#pragma unroll
      for (int n = 0; n < 4; ++n)
        bff[n] = *(const bf16x8*)(&Bs[(wc + n * 16 + lc) * 64 + kk * 32 + lr * 8]);
#pragma unroll
      for (int m = 0; m < 4; ++m)
#pragma unroll
        for (int n = 0; n < 4; ++n)
          acc[m][n] = MFMA16(af[m], bff[n], acc[m][n]);
    }
  }

  const int jr = lr * 4;
#pragma unroll
  for (int m = 0; m < 4; ++m) {
    const int r0  = m0 + wr + m * 16 + jr;
    const int b   = r0 / 1280;
    const int np0 = r0 - b * 1280;          // global key, 4-aligned
    const int kt  = np0 >> 5;
    const int kl  = np0 & 31;               // key-in-tile, 4-aligned
#pragma unroll
    for (int n = 0; n < 4; ++n) {
      const int c    = n0 + wc + n * 16 + lc;
      const float al = alpha[c], be = beta[c];
      const int head = c / 192;
      const int off  = c - head * 192;
      const size_t bh = (size_t)(b * 8 + head);
      if (off < 64) {
        const size_t base = ((bh * 40 + kt) << 11);
#pragma unroll
        for (int j = 0; j < 4; ++j) {
          const int r = kl + j;
          k_buf[base + (r << 6) + ((((off >> 3) ^ (r & 7)) << 3)) + (off & 7)] =
              f2bf(acc[m][n][j] * al + be);
        }
      } else {
        const int d = off - 64;
        u16x4 pk;
#pragma unroll
        for (int j = 0; j < 4; ++j) pk[j] = f2bf(acc[m][n][j] * al + be);
        const size_t dst = ((size_t)(bh * 40 + kt) << 12) + d * 32 +
                           ((((kl >> 2) + (d >> 1)) & 7) << 2);
        *(u16x4*)(&vt_buf[dst]) = pk;
      }
    }
  }
}

// ---------------- GEMM 2: q = subsample(x) @ W_q^T, BN, *(0.125*log2e folded) ----------------

__device__ __forceinline__ int sub_src_row(int qr) {
  if (qr < 256) return ((qr >> 4) * 64) + ((qr & 15) * 2);
  int rr = qr - 256;
  return 1024 + ((rr >> 3) * 32) + ((rr & 7) * 2);
}

__global__ __launch_bounds__(256) void gemm_q(
    const u16* __restrict__ X, const u16* __restrict__ Wt,
    const float* __restrict__ alpha, const float* __restrict__ beta,
    u16* __restrict__ q_buf) {
  __shared__ __align__(16) u16 As[128 * 64];
  __shared__ __align__(16) u16 Bs[128 * 64];
  const int tid  = threadIdx.x;
  const int lane = tid & 63;
  const int w    = tid >> 6;
  const int wr   = (w >> 1) * 64, wc = (w & 1) * 64;
  const int lr   = lane >> 4, lc = lane & 15;
  const int m0   = blockIdx.x * 128;
  const int n0   = blockIdx.y * 128;
  const int scol  = (lane & 7) * 8;
  f32x4 acc[4][4] = {};

  for (int kt = 0; kt < 256; kt += 64) {
    if (kt) __syncthreads();
#pragma unroll
    for (int i = 0; i < 4; ++i) {
      const int row = w * 32 + i * 8 + (lane >> 3);
      const int gr  = m0 + row;
      const int bb  = gr / 320;
      const int qr  = gr - bb * 320;
      async16(&As[(w * 32 + i * 8) * 64],
              X + (size_t)(bb * 1280 + sub_src_row(qr)) * 256 + kt + scol);
      async16(&Bs[(w * 32 + i * 8) * 64], Wt + (size_t)(n0 + row) * 256 + kt + scol);
    }
    __syncthreads();
#pragma unroll
    for (int kk = 0; kk < 2; ++kk) {
      bf16x8 af[4], bff[4];
#pragma unroll
      for (int m = 0; m < 4; ++m)
        af[m] = *(const bf16x8*)(&As[(wr + m * 16 + lc) * 64 + kk * 32 + lr * 8]);
#pragma unroll
      for (int n = 0; n < 4; ++n)
        bff[n] = *(const bf16x8*)(&Bs[(wc + n * 16 + lc) * 64 + kk * 32 + lr * 8]);
#pragma unroll
      for (int m = 0; m < 4; ++m)
#pragma unroll
        for (int n = 0; n < 4; ++n)
          acc[m][n] = MFMA16(af[m], bff[n], acc[m][n]);
    }
  }

  const int jr = lr * 4;
#pragma unroll
  for (int m = 0; m < 4; ++m) {
#pragma unroll
    for (int n = 0; n < 4; ++n) {
      const int c    = n0 + wc + n * 16 + lc;   // < 512
      const float al = alpha[c], be = beta[c];
      const int head = c >> 6, kd = c & 63;
#pragma unroll
      for (int j = 0; j < 4; ++j) {
        const int r  = m0 + wr + m * 16 + jr + j;
        const int b  = r / 320;
        const int qr = r - b * 320;
        q_buf[((size_t)(b * 8 + head) * 320 + qr) * 64 + kd] = f2bf(acc[m][n][j] * al + be);
      }
    }
  }
}

// ---------------- attention ----------------
// Block = 64 q-rows (4 waves x 16), grid 1280 = 5 blocks/CU. KVBLK=32, 40 tiles.
// Swapped QK^T, in-reg P, K=16 PV, no-max softmax with RAW v_exp_f32 (exp2
// builtin; libm exp2f expands to multi-instr fixups on the 1/4-rate trans pipe),
// bf16 bias as MFMA C-init (f32 bias doubled FETCH in R11 - reverted).
// Ring-2 LDS (24KB), global_load_lds staging, counted vmcnt(1)+s_barrier.

__global__ __launch_bounds__(256) void attn_kernel(
    const u16* __restrict__ q_buf, const u16* __restrict__ kphys,
    const u16* __restrict__ vphys, const u16* __restrict__ bias_frag,
    u16* __restrict__ o_buf) {
  __shared__ __align__(16) u16 Kb[2][2048];
  __shared__ __align__(16) u16 Vb[2][4096];
  const int tid  = threadIdx.x;
  const int lane = tid & 63;
  const int w    = tid >> 6;
  const int lr   = lane >> 4, lc = lane & 15, jr = lr * 4;
  // XCD swizzle: 160 consecutive per XCD -> 32 (b,h) groups of 5 q-tiles
  const int g   = blockIdx.x;
  const int f   = (g & 7) * 160 + (g >> 3);
  const int qt  = f % 5;
  const int bh_ = f / 5;
  const int h = bh_ & 7, b = bh_ >> 3;
  const size_t bh = (size_t)bh_;
  const int q0 = qt * 64 + w * 16;

  bf16x8 bq0, bq1;
  {
    const u16* qp = q_buf + (bh * 320 + q0 + lc) * 64 + lr * 8;
    bq0 = *(const bf16x8*)(qp);
    bq1 = *(const bf16x8*)(qp + 32);
  }

  f32x4 oacc[8] = {};
  float lacc = 0.f;

  const u16* kt_base   = kphys + bh * (40 * 2048);
  const u16* vt_base   = vphys + bh * (40 * 4096);
  const u16* bias_base = bias_frag + (((size_t)(h * 5 + qt) * 40) * 256 + tid) * 8;

  // hoisted lane-constant LDS offsets (u16 elements)
  const int ko0 = lc * 64 + ((lr ^ (lc & 7)) << 3);
  const int ko1 = lc * 64 + (((4 + lr) ^ (lc & 7)) << 3);
  const int po0 = lc * 32 + ((lr + (lc >> 1)) & 7) * 4;
  const int po1 = lc * 32 + ((4 + lr + (lc >> 1)) & 7) * 4;

  u16x8 bbA, bbB;

  auto issue = [&](int buf, int kt) {
    async16(&Kb[buf][w * 512], kt_base + kt * 2048 + w * 512 + lane * 8);
    const u16* vs = vt_base + kt * 4096 + (w * 2) * 512 + lane * 8;
    async16(&Vb[buf][(w * 2) * 512], vs);
    async16(&Vb[buf][(w * 2 + 1) * 512], vs + 512);
  };
  auto gbias = [&](int kt, u16x8* dst) {
    *dst = *(const u16x8*)(bias_base + (size_t)kt * 2048);
  };

  auto compute = [&](int buf, const u16x8* bb) {
    const u16* Ksb = Kb[buf];
    const u16* Vsb = Vb[buf];
    const u16* bptr = (const u16*)bb;

    // S^T = K Q^T with bf16 bias as C-init; n in {0,1} key-chunks of 16
    f32x4 s[2];
    __builtin_amdgcn_s_setprio(1);
#pragma unroll
    for (int n = 0; n < 2; ++n) {
      const bf16x8 kf0 = *(const bf16x8*)(Ksb + n * 1024 + ko0);
      const bf16x8 kf1 = *(const bf16x8*)(Ksb + n * 1024 + ko1);
      f32x4 t;
#pragma unroll
      for (int j = 0; j < 4; ++j) t[j] = bf2f(bptr[n * 4 + j]);
      t = MFMA16(kf0, bq0, t);
      t = MFMA16(kf1, bq1, t);
      s[n] = t;
    }
    __builtin_amdgcn_s_setprio(0);

    // P = exp2(S') in-register (raw v_exp_f32); in-lane partial row-sum
    s16x4 pa[2];
    float ssum = 0.f;
#pragma unroll
    for (int n = 0; n < 2; ++n) {
      u16x4 pk;
#pragma unroll
      for (int j = 0; j < 4; ++j) {
        const float e = EXP2(s[n][j]);
        ssum += e;
        pk[j] = f2bf(e);
      }
      pa[n] = __builtin_bit_cast(s16x4, pk);
    }
    lacc += ssum;

    // PV: addresses = 2 lane regs + compile-time immediates; conflict-free
    __builtin_amdgcn_s_setprio(1);
#pragma unroll
    for (int nc = 0; nc < 8; ++nc) {
      const u16* vrow = Vsb + nc * 512;
      const s16x4 vf0 = __builtin_bit_cast(s16x4, *(const u16x4*)(vrow + po0));
      const s16x4 vf1 = __builtin_bit_cast(s16x4, *(const u16x4*)(vrow + po1));
      oacc[nc] = MFMA16K16(pa[0], vf0, oacc[nc]);
      oacc[nc] = MFMA16K16(pa[1], vf1, oacc[nc]);
    }
    __builtin_amdgcn_s_setprio(0);
  };

#define WAITBAR(N)                                                       \
  asm volatile("s_waitcnt vmcnt(" #N ") lgkmcnt(0)" ::: "memory");       \
  __builtin_amdgcn_s_barrier();

  issue(0, 0);
  gbias(0, &bbA);
  WAITBAR(1)   // tile0's 3 DMA done; bias0 may linger (compiler waits at use)

#pragma unroll 1
  for (int t = 0; t < 40; t += 2) {
    issue(1, t + 1);
    gbias(t + 1, &bbB);
    compute(0, &bbA);
    WAITBAR(1)
    if (t + 2 < 40) { issue(0, t + 2); gbias(t + 2, &bbA); }
    compute(1, &bbB);
    WAITBAR(1)
  }
#undef WAITBAR

  lacc += __shfl_xor(lacc, 16);
  lacc += __shfl_xor(lacc, 32);
  float invl[4];
#pragma unroll
  for (int j = 0; j < 4; ++j) invl[j] = 1.f / __shfl(lacc, jr + j);

#pragma unroll
  for (int nc = 0; nc < 8; ++nc)
#pragma unroll
    for (int j = 0; j < 4; ++j) {
      const float xv = oacc[nc][j] * invl[j];
      const float hs = xv * fminf(fmaxf(xv + 3.f, 0.f), 6.f) * (1.f / 6.f);
      o_buf[((size_t)b * 320 + q0 + jr + j) * 1024 + h * 128 + nc * 16 + lc] = f2bf(hs);
    }
}

// ---------------- GEMM 3: out = hswish(o) @ W_p^T, BN (f32 out) ----------------

__global__ __launch_bounds__(256) void gemm_p(
    const u16* __restrict__ O, const u16* __restrict__ Wt,
    const float* __restrict__ alpha, const float* __restrict__ beta,
    float* __restrict__ out) {
  __shared__ __align__(16) u16 As[128 * 64];
  __shared__ __align__(16) u16 Bs[128 * 64];
  const int tid  = threadIdx.x;
  const int lane = tid & 63;
  const int w    = tid >> 6;
  const int wr   = (w >> 1) * 64, wc = (w & 1) * 64;
  const int lr   = lane >> 4, lc = lane & 15;
  const int m0   = blockIdx.x * 128;
  const int n0   = blockIdx.y * 128;
  const int scol  = (lane & 7) * 8;
  f32x4 acc[4][4] = {};

  for (int kt = 0; kt < 1024; kt += 64) {
    if (kt) __syncthreads();
#pragma unroll
    for (int i = 0; i < 4; ++i) {
      const int row = w * 32 + i * 8 + (lane >> 3);
      async16(&As[(w * 32 + i * 8) * 64], O  + (size_t)(m0 + row) * 1024 + kt + scol);
      async16(&Bs[(w * 32 + i * 8) * 64], Wt + (size_t)(n0 + row) * 1024 + kt + scol);
    }
    __syncthreads();
#pragma unroll
    for (int kk = 0; kk < 2; ++kk) {
      bf16x8 af[4], bff[4];
#pragma unroll
      for (int m = 0; m < 4; ++m)
        af[m] = *(const bf16x8*)(&As[(wr + m * 16 + lc) * 64 + kk * 32 + lr * 8]);
#pragma unroll
      for (int n = 0; n < 4; ++n)
        bff[n] = *(const bf16x8*)(&Bs[(wc + n * 16 + lc) * 64 + kk * 32 + lr * 8]);
#pragma unroll
      for (int m = 0; m < 4; ++m)
#pragma unroll
        for (int n = 0; n < 4; ++n)
          acc[m][n] = MFMA16(af[m], bff[n], acc[m][n]);
    }
  }

  const int jr = lr * 4;
#pragma unroll
  for (int m = 0; m < 4; ++m) {
#pragma unroll
    for (int n = 0; n < 4; ++n) {
      const int c = n0 + wc + n * 16 + lc;   // < 384
      const float al = alpha[c], be = beta[c];
#pragma unroll
      for (int j = 0; j < 4; ++j) {
        const int r = m0 + wr + m * 16 + jr + j;
        out[(size_t)r * 384 + c] = acc[m][n][j] * al + be;
      }
    }
  }
}

// ---------------- launch ----------------

extern "C" void kernel_launch(void* const* d_in, const int* in_sizes, int n_in,
                              void* d_out, int out_size, void* d_ws, size_t ws_size,
                              hipStream_t stream) {
  const float* x      = (const float*)d_in[0];
  const float* W_kv   = (const float*)d_in[1];
  const float* g_kv   = (const float*)d_in[2];
  const float* b_kv   = (const float*)d_in[3];
  const float* rm_kv  = (const float*)d_in[4];
  const float* rv_kv  = (const float*)d_in[5];
  const float* W_q    = (const float*)d_in[6];
  const float* g_q    = (const float*)d_in[7];
  const float* b_q    = (const float*)d_in[8];
  const float* rm_q   = (const float*)d_in[9];
  const float* rv_q   = (const float*)d_in[10];
  const float* W_p    = (const float*)d_in[11];
  const float* g_p    = (const float*)d_in[12];
  const float* b_p    = (const float*)d_in[13];
  const float* rm_p   = (const float*)d_in[14];
  const float* rv_p   = (const float*)d_in[15];
  const float* attn_bias = (const float*)d_in[16];
  const int*   bias_idxs = (const int*)d_in[17];
  const int n_off = in_sizes[16] / 8;

  char* ws = (char*)d_ws;
  size_t off = 0;
  auto alloc = [&](size_t bytes) -> void* {
    void* p = ws + off;
    off += (bytes + 255) & ~(size_t)255;
    return p;
  };
  u16* x_bf    = (u16*)alloc((size_t)40960 * 256 * 2);
  u16* wkv_bf  = (u16*)alloc((size_t)1536 * 256 * 2);
  u16* wq_bf   = (u16*)alloc((size_t)512 * 256 * 2);
  u16* wp_bf   = (u16*)alloc((size_t)384 * 1024 * 2);
  float* al_kv = (float*)alloc(1536 * 4);
  float* be_kv = (float*)alloc(1536 * 4);
  float* al_q  = (float*)alloc(512 * 4);
  float* be_q  = (float*)alloc(512 * 4);
  float* al_p  = (float*)alloc(384 * 4);
  float* be_p  = (float*)alloc(384 * 4);
  u16* k_buf   = (u16*)alloc((size_t)256 * 40 * 2048 * 2);
  u16* vt_buf  = (u16*)alloc((size_t)256 * 40 * 4096 * 2);
  u16* q_buf   = (u16*)alloc((size_t)32 * 8 * 320 * 64 * 2);
  u16* bias_fr = (u16*)alloc((size_t)8 * 5 * 40 * 256 * 8 * 2);
  u16* o_buf   = (u16*)alloc((size_t)32 * 320 * 1024 * 2);
  (void)ws_size; (void)n_in; (void)out_size;

  cvt_f32_bf16<<<(2621440 + 255) / 256, 256, 0, stream>>>(x, x_bf, 2621440);
  prep_fused<<<906, 256, 0, stream>>>(
      W_kv, W_q, W_p, wkv_bf, wq_bf, wp_bf,
      g_kv, b_kv, rm_kv, rv_kv, al_kv, be_kv,
      g_q, b_q, rm_q, rv_q, al_q, be_q,
      g_p, b_p, rm_p, rv_p, al_p, be_p);
  bias_expand_frag<<<(3276800 + 255) / 256, 256, 0, stream>>>(attn_bias, bias_idxs, bias_fr, n_off);

  gemm_kv<<<dim3(320, 12), 256, 0, stream>>>(x_bf, wkv_bf, al_kv, be_kv, k_buf, vt_buf);
  gemm_q<<<dim3(80, 4), 256, 0, stream>>>(x_bf, wq_bf, al_q, be_q, q_buf);
  attn_kernel<<<dim3(1280), 256, 0, stream>>>(q_buf, k_buf, vt_buf, bias_fr, o_buf);
  gemm_p<<<dim3(80, 3), 256, 0, stream>>>(o_buf, wp_bf, al_p, be_p, (float*)d_out);
}

// Round 13
// 182.945 us; speedup vs baseline: 1.3184x; 1.0583x over previous
//
#include <hip/hip_runtime.h>
#include <hip/hip_bf16.h>
#include <cstdint>
#include <cstddef>

typedef unsigned short u16;
typedef __bf16 bf16x8 __attribute__((ext_vector_type(8)));
typedef float  f32x4  __attribute__((ext_vector_type(4)));
typedef u16    u16x8  __attribute__((ext_vector_type(8)));
typedef u16    u16x4  __attribute__((ext_vector_type(4)));
typedef short  s16x4  __attribute__((ext_vector_type(4)));

#define MFMA16(A_, B_, C_) __builtin_amdgcn_mfma_f32_16x16x32_bf16((A_), (B_), (C_), 0, 0, 0)
#define MFMA16K16(A_, B_, C_) __builtin_amdgcn_mfma_f32_16x16x16bf16_1k((A_), (B_), (C_), 0, 0, 0)

#define LOG2E 1.4426950408889634f

#if __has_builtin(__builtin_amdgcn_exp2f)
#define EXP2(x) __builtin_amdgcn_exp2f(x)
#else
#define EXP2(x) exp2f(x)
#endif

__device__ __forceinline__ u16 f2bf(float f) {
  return __builtin_bit_cast(u16, (__bf16)f);
}
__device__ __forceinline__ float bf2f(u16 v) {
  return (float)__builtin_bit_cast(__bf16, v);
}

// async global->LDS, 16B per lane. lds must be wave-uniform base; HW adds lane*16.
__device__ __forceinline__ void async16(u16* lds, const u16* g) {
  __builtin_amdgcn_global_load_lds(
      (const __attribute__((address_space(1))) unsigned int*)g,
      (__attribute__((address_space(3))) unsigned int*)lds, 16, 0, 0);
}

// ---------------- fused prep: x cvt + weight cvts + bn folds + bias table ----------------

__device__ __forceinline__ void cvt4(const float* src, u16* dst, int i) {
  const float4 v = ((const float4*)src)[i];
  u16x4 o;
  o[0] = f2bf(v.x); o[1] = f2bf(v.y); o[2] = f2bf(v.z); o[3] = f2bf(v.w);
  ((u16x4*)dst)[i] = o;
}

__device__ __forceinline__ void bn1(const float* g, const float* b, const float* rm,
                                    const float* rv, float* alpha, float* beta,
                                    int i, float scale) {
  float a0 = g[i] * rsqrtf(rv[i] + 1e-5f);
  alpha[i] = a0 * scale;
  beta[i]  = (b[i] - rm[i] * a0) * scale;
}

__global__ void prep_all(
    const float* __restrict__ x, u16* __restrict__ x_bf,
    const float* __restrict__ Wkv, const float* __restrict__ Wq, const float* __restrict__ Wp,
    u16* __restrict__ wkv_bf, u16* __restrict__ wq_bf, u16* __restrict__ wp_bf,
    const float* __restrict__ g_kv, const float* __restrict__ b_kv,
    const float* __restrict__ rm_kv, const float* __restrict__ rv_kv,
    float* __restrict__ al_kv, float* __restrict__ be_kv,
    const float* __restrict__ g_q, const float* __restrict__ b_q,
    const float* __restrict__ rm_q, const float* __restrict__ rv_q,
    float* __restrict__ al_q, float* __restrict__ be_q,
    const float* __restrict__ g_p, const float* __restrict__ b_p,
    const float* __restrict__ rm_p, const float* __restrict__ rv_p,
    float* __restrict__ al_p, float* __restrict__ be_p,
    const float* __restrict__ attn_bias, const int* __restrict__ idxs,
    u16* __restrict__ bias_frag, int n_off) {
  const int bid = blockIdx.x, t = threadIdx.x;
  if (bid < 10240) {                       // x: 2621440 float4
    cvt4(x, x_bf, bid * 256 + t);
  } else if (bid < 10624) {
    cvt4(Wkv, wkv_bf, (bid - 10240) * 256 + t);
  } else if (bid < 10752) {
    cvt4(Wq, wq_bf, (bid - 10624) * 256 + t);
  } else if (bid < 11136) {
    cvt4(Wp, wp_bf, (bid - 10752) * 256 + t);
  } else if (bid < 11142) {
    bn1(g_kv, b_kv, rm_kv, rv_kv, al_kv, be_kv, (bid - 11136) * 256 + t, 1.0f);
  } else if (bid < 11144) {
    bn1(g_q, b_q, rm_q, rv_q, al_q, be_q, (bid - 11142) * 256 + t, 0.125f * LOG2E);
  } else if (bid < 11146) {
    const int i = (bid - 11144) * 256 + t;
    if (i < 384) bn1(g_p, b_p, rm_p, rv_p, al_p, be_p, i, 1.0f);
  } else {
    // bias (x log2e, bf16) in PV-fragment order: [h][qt5][kt40][tid256][nn2*j4]
    int i = (bid - 11146) * 256 + t;
    if (i < 8 * 5 * 40 * 256 * 8) {
      const int e8  = i & 7;
      const int nn  = e8 >> 2;
      const int j   = e8 & 3;
      const int tid = (i >> 3) & 255;
      int v = i >> 11;
      const int kt = v % 40; v /= 40;
      const int qt = v % 5;
      const int h  = v / 5;
      const int w = tid >> 6, lr = (tid >> 4) & 3, lc = tid & 15;
      const int q = qt * 64 + w * 16 + lc;
      const int k = kt * 32 + nn * 16 + lr * 4 + j;
      bias_frag[i] = f2bf(attn_bias[h * n_off + idxs[q * 1280 + k]] * LOG2E);
    }
  }
}

// ---------------- fused GEMM: kv (with LDS-repack epilogue) + q ----------------
// K phys per (bh, kt32): 32 rows x 64ch, 16B chunk c at c^(r&7)     (b128 reads)
// V phys: 128 d x 32 keys, 8B chunk hc at (hc+(d>>1))&7             (b64 reads)
// kv epilogue: scatter acc -> LDS in phys order, then coalesced 16B/lane copy-out
// (old path: 64 scalar 2B + 16 scattered 8B global stores/lane -> ~16x write amp).

__device__ __forceinline__ void gemm_kv_part(
    u16* S, int bid,
    const u16* __restrict__ A, const u16* __restrict__ Wt,
    const float* __restrict__ alpha, const float* __restrict__ beta,
    u16* __restrict__ k_buf, u16* __restrict__ vt_buf) {
  u16* As = S;
  u16* Bs = S + 8192;
  const int tid  = threadIdx.x;
  const int lane = tid & 63;
  const int w    = tid >> 6;
  const int wr   = (w >> 1) * 64, wc = (w & 1) * 64;
  const int lr   = lane >> 4, lc = lane & 15;
  const int m0   = (bid % 320) * 128;
  const int n0   = (bid / 320) * 128;
  const int scol  = (lane & 7) * 8;
  f32x4 acc[4][4] = {};

  for (int kt = 0; kt < 256; kt += 64) {
    if (kt) __syncthreads();
#pragma unroll
    for (int i = 0; i < 4; ++i) {
      const int row = w * 32 + i * 8 + (lane >> 3);
      async16(&As[(w * 32 + i * 8) * 64], A  + (size_t)(m0 + row) * 256 + kt + scol);
      async16(&Bs[(w * 32 + i * 8) * 64], Wt + (size_t)(n0 + row) * 256 + kt + scol);
    }
    __syncthreads();
#pragma unroll
    for (int kk = 0; kk < 2; ++kk) {
      bf16x8 af[4], bff[4];
#pragma unroll
      for (int m = 0; m < 4; ++m)
        af[m] = *(const bf16x8*)(&As[(wr + m * 16 + lc) * 64 + kk * 32 + lr * 8]);
#pragma unroll
      for (int n = 0; n < 4; ++n)
        bff[n] = *(const bf16x8*)(&Bs[(wc + n * 16 + lc) * 64 + kk * 32 + lr * 8]);
#pragma unroll
      for (int m = 0; m < 4; ++m)
#pragma unroll
        for (int n = 0; n < 4; ++n)
          acc[m][n] = MFMA16(af[m], bff[n], acc[m][n]);
    }
  }

  // ---- epilogue: BN + repack to LDS in phys order, then coalesced copy-out ----
  __syncthreads();                         // all waves done reading As/Bs
  const int jr   = lr * 4;
  const int b    = m0 / 1280;
  const int np0  = m0 - b * 1280;          // multiple of 128
  const int kt0  = np0 >> 5;
  const int hh   = w & 1;                  // this wave's 64-col half
  const int c0   = n0 + hh * 64;
  const int head = c0 / 192;
  const int rem  = c0 - head * 192;        // 0 = K, 64/128 = V half
  u16* R = S + hh * 8192;
  (void)head;

#pragma unroll
  for (int m = 0; m < 4; ++m) {
    const int lrow = (w >> 1) * 64 + m * 16 + jr;  // 0..127
    const int ktl  = lrow >> 5;
    const int kl   = lrow & 31;                    // 4-aligned
#pragma unroll
    for (int n = 0; n < 4; ++n) {
      const int ch = n * 16 + lc;                  // 0..63 within half
      const int c  = c0 + ch;
      const float al = alpha[c], be = beta[c];
      if (rem == 0) {
#pragma unroll
        for (int j = 0; j < 4; ++j) {
          const int r = kl + j;
          R[ktl * 2048 + (r << 6) + (((ch >> 3) ^ (r & 7)) << 3) + (ch & 7)] =
              f2bf(acc[m][n][j] * al + be);
        }
      } else {
        const int d = (rem - 64) + ch;
        u16x4 pk;
#pragma unroll
        for (int j = 0; j < 4; ++j) pk[j] = f2bf(acc[m][n][j] * al + be);
        *(u16x4*)(&R[ktl * 2048 + ch * 32 + ((((kl >> 2) + (d >> 1)) & 7) << 2)]) = pk;
      }
    }
  }
  __syncthreads();

#pragma unroll
  for (int g2 = 0; g2 < 2; ++g2) {
    const int c0g  = n0 + g2 * 64;
    const int hd   = c0g / 192;
    const int remg = c0g - hd * 192;
    const size_t bhg = (size_t)(b * 8 + hd);
    const u16* Rg = S + g2 * 8192;
    if (remg == 0) {
      u16* dst = k_buf + ((bhg * 40 + kt0) << 11);
#pragma unroll
      for (int i = 0; i < 4; ++i)
        *(u16x8*)(dst + i * 2048 + tid * 8) = *(const u16x8*)(Rg + i * 2048 + tid * 8);
    } else {
      const int dbase = remg - 64;
#pragma unroll
      for (int i = 0; i < 4; ++i)
        *(u16x8*)(vt_buf + ((bhg * 40 + kt0 + i) << 12) + dbase * 32 + tid * 8) =
            *(const u16x8*)(Rg + i * 2048 + tid * 8);
    }
  }
}

__device__ __forceinline__ int sub_src_row(int qr) {
  if (qr < 256) return ((qr >> 4) * 64) + ((qr & 15) * 2);
  int rr = qr - 256;
  return 1024 + ((rr >> 3) * 32) + ((rr & 7) * 2);
}

__device__ __forceinline__ void gemm_q_part(
    u16* S, int id2,
    const u16* __restrict__ X, const u16* __restrict__ Wt,
    const float* __restrict__ alpha, const float* __restrict__ beta,
    u16* __restrict__ q_buf) {
  u16* As = S;
  u16* Bs = S + 8192;
  const int tid  = threadIdx.x;
  const int lane = tid & 63;
  const int w    = tid >> 6;
  const int wr   = (w >> 1) * 64, wc = (w & 1) * 64;
  const int lr   = lane >> 4, lc = lane & 15;
  const int m0   = (id2 % 80) * 128;
  const int n0   = (id2 / 80) * 128;
  const int scol  = (lane & 7) * 8;
  f32x4 acc[4][4] = {};

  for (int kt = 0; kt < 256; kt += 64) {
    if (kt) __syncthreads();
#pragma unroll
    for (int i = 0; i < 4; ++i) {
      const int row = w * 32 + i * 8 + (lane >> 3);
      const int gr  = m0 + row;
      const int bb  = gr / 320;
      const int qr  = gr - bb * 320;
      async16(&As[(w * 32 + i * 8) * 64],
              X + (size_t)(bb * 1280 + sub_src_row(qr)) * 256 + kt + scol);
      async16(&Bs[(w * 32 + i * 8) * 64], Wt + (size_t)(n0 + row) * 256 + kt + scol);
    }
    __syncthreads();
#pragma unroll
    for (int kk = 0; kk < 2; ++kk) {
      bf16x8 af[4], bff[4];
#pragma unroll
      for (int m = 0; m < 4; ++m)
        af[m] = *(const bf16x8*)(&As[(wr + m * 16 + lc) * 64 + kk * 32 + lr * 8]);
#pragma unroll
      for (int n = 0; n < 4; ++n)
        bff[n] = *(const bf16x8*)(&Bs[(wc + n * 16 + lc) * 64 + kk * 32 + lr * 8]);
#pragma unroll
      for (int m = 0; m < 4; ++m)
#pragma unroll
        for (int n = 0; n < 4; ++n)
          acc[m][n] = MFMA16(af[m], bff[n], acc[m][n]);
    }
  }

  const int jr = lr * 4;
#pragma unroll
  for (int m = 0; m < 4; ++m) {
#pragma unroll
    for (int n = 0; n < 4; ++n) {
      const int c    = n0 + wc + n * 16 + lc;   // < 512
      const float al = alpha[c], be = beta[c];
      const int head = c >> 6, kd = c & 63;
#pragma unroll
      for (int j = 0; j < 4; ++j) {
        const int r  = m0 + wr + m * 16 + jr + j;
        const int b  = r / 320;
        const int qr = r - b * 320;
        q_buf[((size_t)(b * 8 + head) * 320 + qr) * 64 + kd] = f2bf(acc[m][n][j] * al + be);
      }
    }
  }
}

__global__ __launch_bounds__(256) void gemm_kvq(
    const u16* __restrict__ A, const u16* __restrict__ Wkv,
    const float* __restrict__ al_kv, const float* __restrict__ be_kv,
    u16* __restrict__ k_buf, u16* __restrict__ vt_buf,
    const u16* __restrict__ Wq,
    const float* __restrict__ al_q, const float* __restrict__ be_q,
    u16* __restrict__ q_buf) {
  __shared__ __align__(16) u16 S[16384];
  const int bid = blockIdx.x;
  if (bid < 3840) {
    gemm_kv_part(S, bid, A, Wkv, al_kv, be_kv, k_buf, vt_buf);
  } else {
    gemm_q_part(S, bid - 3840, A, Wq, al_q, be_q, q_buf);
  }
}

// ---------------- attention (R12, unchanged) ----------------

__global__ __launch_bounds__(256) void attn_kernel(
    const u16* __restrict__ q_buf, const u16* __restrict__ kphys,
    const u16* __restrict__ vphys, const u16* __restrict__ bias_frag,
    u16* __restrict__ o_buf) {
  __shared__ __align__(16) u16 Kb[2][2048];
  __shared__ __align__(16) u16 Vb[2][4096];
  const int tid  = threadIdx.x;
  const int lane = tid & 63;
  const int w    = tid >> 6;
  const int lr   = lane >> 4, lc = lane & 15, jr = lr * 4;
  const int g   = blockIdx.x;
  const int f   = (g & 7) * 160 + (g >> 3);
  const int qt  = f % 5;
  const int bh_ = f / 5;
  const int h = bh_ & 7, b = bh_ >> 3;
  const size_t bh = (size_t)bh_;
  const int q0 = qt * 64 + w * 16;

  bf16x8 bq0, bq1;
  {
    const u16* qp = q_buf + (bh * 320 + q0 + lc) * 64 + lr * 8;
    bq0 = *(const bf16x8*)(qp);
    bq1 = *(const bf16x8*)(qp + 32);
  }

  f32x4 oacc[8] = {};
  float lacc = 0.f;

  const u16* kt_base   = kphys + bh * (40 * 2048);
  const u16* vt_base   = vphys + bh * (40 * 4096);
  const u16* bias_base = bias_frag + (((size_t)(h * 5 + qt) * 40) * 256 + tid) * 8;

  const int ko0 = lc * 64 + ((lr ^ (lc & 7)) << 3);
  const int ko1 = lc * 64 + (((4 + lr) ^ (lc & 7)) << 3);
  const int po0 = lc * 32 + ((lr + (lc >> 1)) & 7) * 4;
  const int po1 = lc * 32 + ((4 + lr + (lc >> 1)) & 7) * 4;

  u16x8 bbA, bbB;

  auto issue = [&](int buf, int kt) {
    async16(&Kb[buf][w * 512], kt_base + kt * 2048 + w * 512 + lane * 8);
    const u16* vs = vt_base + kt * 4096 + (w * 2) * 512 + lane * 8;
    async16(&Vb[buf][(w * 2) * 512], vs);
    async16(&Vb[buf][(w * 2 + 1) * 512], vs + 512);
  };
  auto gbias = [&](int kt, u16x8* dst) {
    *dst = *(const u16x8*)(bias_base + (size_t)kt * 2048);
  };

  auto compute = [&](int buf, const u16x8* bb) {
    const u16* Ksb = Kb[buf];
    const u16* Vsb = Vb[buf];
    const u16* bptr = (const u16*)bb;

    f32x4 s[2];
    __builtin_amdgcn_s_setprio(1);
#pragma unroll
    for (int n = 0; n < 2; ++n) {
      const bf16x8 kf0 = *(const bf16x8*)(Ksb + n * 1024 + ko0);
      const bf16x8 kf1 = *(const bf16x8*)(Ksb + n * 1024 + ko1);
      f32x4 t;
#pragma unroll
      for (int j = 0; j < 4; ++j) t[j] = bf2f(bptr[n * 4 + j]);
      t = MFMA16(kf0, bq0, t);
      t = MFMA16(kf1, bq1, t);
      s[n] = t;
    }
    __builtin_amdgcn_s_setprio(0);

    s16x4 pa[2];
    float ssum = 0.f;
#pragma unroll
    for (int n = 0; n < 2; ++n) {
      u16x4 pk;
#pragma unroll
      for (int j = 0; j < 4; ++j) {
        const float e = EXP2(s[n][j]);
        ssum += e;
        pk[j] = f2bf(e);
      }
      pa[n] = __builtin_bit_cast(s16x4, pk);
    }
    lacc += ssum;

    __builtin_amdgcn_s_setprio(1);
#pragma unroll
    for (int nc = 0; nc < 8; ++nc) {
      const u16* vrow = Vsb + nc * 512;
      const s16x4 vf0 = __builtin_bit_cast(s16x4, *(const u16x4*)(vrow + po0));
      const s16x4 vf1 = __builtin_bit_cast(s16x4, *(const u16x4*)(vrow + po1));
      oacc[nc] = MFMA16K16(pa[0], vf0, oacc[nc]);
      oacc[nc] = MFMA16K16(pa[1], vf1, oacc[nc]);
    }
    __builtin_amdgcn_s_setprio(0);
  };

#define WAITBAR(N)                                                       \
  asm volatile("s_waitcnt vmcnt(" #N ") lgkmcnt(0)" ::: "memory");       \
  __builtin_amdgcn_s_barrier();

  issue(0, 0);
  gbias(0, &bbA);
  WAITBAR(1)

#pragma unroll 1
  for (int t = 0; t < 40; t += 2) {
    issue(1, t + 1);
    gbias(t + 1, &bbB);
    compute(0, &bbA);
    WAITBAR(1)
    if (t + 2 < 40) { issue(0, t + 2); gbias(t + 2, &bbA); }
    compute(1, &bbB);
    WAITBAR(1)
  }
#undef WAITBAR

  lacc += __shfl_xor(lacc, 16);
  lacc += __shfl_xor(lacc, 32);
  float invl[4];
#pragma unroll
  for (int j = 0; j < 4; ++j) invl[j] = 1.f / __shfl(lacc, jr + j);

#pragma unroll
  for (int nc = 0; nc < 8; ++nc)
#pragma unroll
    for (int j = 0; j < 4; ++j) {
      const float xv = oacc[nc][j] * invl[j];
      const float hs = xv * fminf(fmaxf(xv + 3.f, 0.f), 6.f) * (1.f / 6.f);
      o_buf[((size_t)b * 320 + q0 + jr + j) * 1024 + h * 128 + nc * 16 + lc] = f2bf(hs);
    }
}

// ---------------- GEMM 3: out = hswish(o) @ W_p^T, BN (f32 out) ----------------

__global__ __launch_bounds__(256) void gemm_p(
    const u16* __restrict__ O, const u16* __restrict__ Wt,
    const float* __restrict__ alpha, const float* __restrict__ beta,
    float* __restrict__ out) {
  __shared__ __align__(16) u16 As[128 * 64];
  __shared__ __align__(16) u16 Bs[128 * 64];
  const int tid  = threadIdx.x;
  const int lane = tid & 63;
  const int w    = tid >> 6;
  const int wr   = (w >> 1) * 64, wc = (w & 1) * 64;
  const int lr   = lane >> 4, lc = lane & 15;
  const int m0   = blockIdx.x * 128;
  const int n0   = blockIdx.y * 128;
  const int scol  = (lane & 7) * 8;
  f32x4 acc[4][4] = {};

  for (int kt = 0; kt < 1024; kt += 64) {
    if (kt) __syncthreads();
#pragma unroll
    for (int i = 0; i < 4; ++i) {
      const int row = w * 32 + i * 8 + (lane >> 3);
      async16(&As[(w * 32 + i * 8) * 64], O  + (size_t)(m0 + row) * 1024 + kt + scol);
      async16(&Bs[(w * 32 + i * 8) * 64], Wt + (size_t)(n0 + row) * 1024 + kt + scol);
    }
    __syncthreads();
#pragma unroll
    for (int kk = 0; kk < 2; ++kk) {
      bf16x8 af[4], bff[4];
#pragma unroll
      for (int m = 0; m < 4; ++m)
        af[m] = *(const bf16x8*)(&As[(wr + m * 16 + lc) * 64 + kk * 32 + lr * 8]);
#pragma unroll
      for (int n = 0; n < 4; ++n)
        bff[n] = *(const bf16x8*)(&Bs[(wc + n * 16 + lc) * 64 + kk * 32 + lr * 8]);
#pragma unroll
      for (int m = 0; m < 4; ++m)
#pragma unroll
        for (int n = 0; n < 4; ++n)
          acc[m][n] = MFMA16(af[m], bff[n], acc[m][n]);
    }
  }

  const int jr = lr * 4;
#pragma unroll
  for (int m = 0; m < 4; ++m) {
#pragma unroll
    for (int n = 0; n < 4; ++n) {
      const int c = n0 + wc + n * 16 + lc;   // < 384
      const float al = alpha[c], be = beta[c];
#pragma unroll
      for (int j = 0; j < 4; ++j) {
        const int r = m0 + wr + m * 16 + jr + j;
        out[(size_t)r * 384 + c] = acc[m][n][j] * al + be;
      }
    }
  }
}

// ---------------- launch ----------------

extern "C" void kernel_launch(void* const* d_in, const int* in_sizes, int n_in,
                              void* d_out, int out_size, void* d_ws, size_t ws_size,
                              hipStream_t stream) {
  const float* x      = (const float*)d_in[0];
  const float* W_kv   = (const float*)d_in[1];
  const float* g_kv   = (const float*)d_in[2];
  const float* b_kv   = (const float*)d_in[3];
  const float* rm_kv  = (const float*)d_in[4];
  const float* rv_kv  = (const float*)d_in[5];
  const float* W_q    = (const float*)d_in[6];
  const float* g_q    = (const float*)d_in[7];
  const float* b_q    = (const float*)d_in[8];
  const float* rm_q   = (const float*)d_in[9];
  const float* rv_q   = (const float*)d_in[10];
  const float* W_p    = (const float*)d_in[11];
  const float* g_p    = (const float*)d_in[12];
  const float* b_p    = (const float*)d_in[13];
  const float* rm_p   = (const float*)d_in[14];
  const float* rv_p   = (const float*)d_in[15];
  const float* attn_bias = (const float*)d_in[16];
  const int*   bias_idxs = (const int*)d_in[17];
  const int n_off = in_sizes[16] / 8;

  char* ws = (char*)d_ws;
  size_t off = 0;
  auto alloc = [&](size_t bytes) -> void* {
    void* p = ws + off;
    off += (bytes + 255) & ~(size_t)255;
    return p;
  };
  u16* x_bf    = (u16*)alloc((size_t)40960 * 256 * 2);
  u16* wkv_bf  = (u16*)alloc((size_t)1536 * 256 * 2);
  u16* wq_bf   = (u16*)alloc((size_t)512 * 256 * 2);
  u16* wp_bf   = (u16*)alloc((size_t)384 * 1024 * 2);
  float* al_kv = (float*)alloc(1536 * 4);
  float* be_kv = (float*)alloc(1536 * 4);
  float* al_q  = (float*)alloc(512 * 4);
  float* be_q  = (float*)alloc(512 * 4);
  float* al_p  = (float*)alloc(384 * 4);
  float* be_p  = (float*)alloc(384 * 4);
  u16* k_buf   = (u16*)alloc((size_t)256 * 40 * 2048 * 2);
  u16* vt_buf  = (u16*)alloc((size_t)256 * 40 * 4096 * 2);
  u16* q_buf   = (u16*)alloc((size_t)32 * 8 * 320 * 64 * 2);
  u16* bias_fr = (u16*)alloc((size_t)8 * 5 * 40 * 256 * 8 * 2);
  u16* o_buf   = (u16*)alloc((size_t)32 * 320 * 1024 * 2);
  (void)ws_size; (void)n_in; (void)out_size;

  prep_all<<<23946, 256, 0, stream>>>(
      x, x_bf, W_kv, W_q, W_p, wkv_bf, wq_bf, wp_bf,
      g_kv, b_kv, rm_kv, rv_kv, al_kv, be_kv,
      g_q, b_q, rm_q, rv_q, al_q, be_q,
      g_p, b_p, rm_p, rv_p, al_p, be_p,
      attn_bias, bias_idxs, bias_fr, n_off);

  gemm_kvq<<<4160, 256, 0, stream>>>(
      x_bf, wkv_bf, al_kv, be_kv, k_buf, vt_buf,
      wq_bf, al_q, be_q, q_buf);

  attn_kernel<<<dim3(1280), 256, 0, stream>>>(q_buf, k_buf, vt_buf, bias_fr, o_buf);
  gemm_p<<<dim3(80, 3), 256, 0, stream>>>(o_buf, wp_bf, al_p, be_p, (float*)d_out);
}